// Round 6
// baseline (431.248 us; speedup 1.0000x reference)
//
#include <hip/hip_runtime.h>
#include <hip/hip_bf16.h>
#include <stdint.h>

// Round 12: two independent low-risk cuts.
//  1) flash: replace shfl_xor(32)-emulated half-swap with real
//     v_permlane32_swap_b32 (T12): 16 ds_bpermute + 32 cndmask on the
//     SERIAL softmax path -> 8 VALU ops, no lgkm waits. __has_builtin
//     guarded (shfl fallback keeps correctness if builtin absent).
//  2) qkv/proj GEMMs: BK=32 -> BK=64 (lA/lB [8][128][8], 32KB LDS,
//     still 2 blocks/CU). Halves the vmcnt(0)-drain-at-barrier frequency
//     (the known ~20% structural stall of this structure) -> matches the
//     m97 874-912 TF reference shape. Epilogues unchanged.
// Round 11 carried: 32x32x16 flash, in-register P (no lP), 2 blocks/CU,
// XCD-pinned grids (FETCH 26.7MB), bitmask mask, exp2-domain softmax.
//
// ws layout:
//   xb      [8192][1024] bf16  @ 0         (dead after qkv -> Ob)
//   wqkv_t  [3072][1024] bf16  @ 16777216  (dead after qkv -> mbits)
//   wout_t  [1024][1024] bf16  @ 23068672
//   Qs      [16][4096][128]    @ 25165824
//   Ks      [16][4096][128]    @ 41943040
//   Vt      [16][128][4096]    @ 58720256

typedef __attribute__((ext_vector_type(8))) short short8;
typedef __attribute__((ext_vector_type(4))) float f32x4;
typedef __attribute__((ext_vector_type(16))) float f32x16;
typedef unsigned int uint2v __attribute__((ext_vector_type(2)));

// DIM^-0.5 * log2(e): S computed in log2 domain, exp via exp2.
#define SCALE_Q 0.0450842200f

__device__ __forceinline__ unsigned short f2bf(float f) {
  union { float f; unsigned int u; } v;
  v.f = f;
  return (unsigned short)((v.u + 0x7fffu + ((v.u >> 16) & 1u)) >> 16);
}

__device__ __forceinline__ unsigned int pkbf2(float a, float b) {
  __hip_bfloat162 h = __float22bfloat162_rn(make_float2(a, b));
  union { __hip_bfloat162 h; unsigned int u; } c;
  c.h = h;
  return c.u;
}

__device__ __forceinline__ void gload_lds16(const void* g, void* l) {
  __builtin_amdgcn_global_load_lds(
      (const __attribute__((address_space(1))) uint32_t*)(uintptr_t)g,
      (__attribute__((address_space(3))) uint32_t*)(uintptr_t)l, 16, 0, 0);
}

__device__ __forceinline__ f32x4 zero4() {
  f32x4 z; z.x = 0.f; z.y = 0.f; z.z = 0.f; z.w = 0.f; return z;
}

// ---------------- conversions ----------------
__global__ __launch_bounds__(256) void k_cvt_x(const float* __restrict__ in,
                                               unsigned short* __restrict__ out) {
  const int t = blockIdx.x * 256 + threadIdx.x;
  const float4 v = ((const float4*)in)[t];
  ushort4 o;
  o.x = f2bf(v.x); o.y = f2bf(v.y); o.z = f2bf(v.z); o.w = f2bf(v.w);
  ((ushort4*)out)[t] = o;
}

__global__ __launch_bounds__(256) void k_cvt_wt(const float* __restrict__ w,
                                                unsigned short* __restrict__ wt,
                                                int Nn) {
  __shared__ float t[32][33];
  const int n0 = blockIdx.x << 5, k0 = blockIdx.y << 5;
  const int c = threadIdx.x & 31, r8 = threadIdx.x >> 5;
#pragma unroll
  for (int i = 0; i < 4; ++i) {
    const int r = (i << 3) + r8;
    t[r][c] = w[(long)(k0 + r) * Nn + n0 + c];
  }
  __syncthreads();
#pragma unroll
  for (int i = 0; i < 4; ++i) {
    const int r = (i << 3) + r8;
    wt[(long)(n0 + r) * 1024 + k0 + c] = f2bf(t[c][r]);
  }
}

// ---------------- mask -> bitmask (ballot) ----------------
__global__ __launch_bounds__(256) void k_mask_bits(
    const int* __restrict__ m, unsigned long long* __restrict__ mb) {
  const int t = blockIdx.x * 256 + threadIdx.x;
  const unsigned long long b = __ballot(m[t] != 0);
  if ((threadIdx.x & 63) == 0) mb[t >> 6] = b;
}

// ---------------- QKV GEMM (BK=64) ----------------
__global__ __launch_bounds__(256, 2) void k_qkv_gemm(
    const unsigned short* __restrict__ A,   // [8192][1024]
    const unsigned short* __restrict__ Bt,  // [3072][1024]
    unsigned short* __restrict__ Qs, unsigned short* __restrict__ Ks,
    unsigned short* __restrict__ Vt) {
  __shared__ __align__(16) unsigned short lA[8][128][8];   // 16 KB
  __shared__ __align__(16) unsigned short lB[8][128][8];   // 16 KB
  const int tid = threadIdx.x;
  const int w = tid >> 6, ln = tid & 63;
  const int m15 = ln & 15, q4 = ln >> 4;
  const int wm = (w >> 1) << 6, wn = (w & 1) << 6;
  const int id = blockIdx.x;
  const int swz = (id & 7) * 192 + (id >> 3);   // XCD-chunked remap
  const int tn = swz % 24, tm = swz / 24;
  const int which = tn >> 3;   // 0=Q 1=K 2=V (uniform per block)
  const int h = tn & 7;

  f32x4 acc[4][4];
#pragma unroll
  for (int i = 0; i < 4; ++i)
#pragma unroll
    for (int j = 0; j < 4; ++j) acc[i][j] = zero4();

#define QKV_STAGE()                                                       \
  {                                                                       \
    _Pragma("unroll")                                                     \
    for (int c = 0; c < 4; ++c) {                                         \
      const int p = ((c * 4 + w) << 10) + (ln << 4);                      \
      const int g = p >> 11;                                              \
      const int r = (p & 2047) >> 4;                                      \
      gload_lds16(A + ((long)tm * 128 + r) * 1024 + kb + g * 8,           \
                  (char*)&lA[0][0][0] + p);                               \
      gload_lds16(Bt + ((long)tn * 128 + r) * 1024 + kb + g * 8,          \
                  (char*)&lB[0][0][0] + p);                               \
    }                                                                     \
  }

  if (which == 2) {
    for (int kb = 0; kb < 1024; kb += 64) {
      __syncthreads();
      QKV_STAGE();
      __syncthreads();
#pragma unroll
      for (int kk = 0; kk < 2; ++kk) {
        short8 afr[4], bfr[4];
#pragma unroll
        for (int i = 0; i < 4; ++i)
          afr[i] = *(const short8*)&lA[kk * 4 + q4][wm + i * 16 + m15][0];
#pragma unroll
        for (int j = 0; j < 4; ++j)
          bfr[j] = *(const short8*)&lB[kk * 4 + q4][wn + j * 16 + m15][0];
#pragma unroll
        for (int i = 0; i < 4; ++i)
#pragma unroll
          for (int j = 0; j < 4; ++j)
            acc[i][j] = __builtin_amdgcn_mfma_f32_16x16x32_bf16(
                afr[i], bfr[j], acc[i][j], 0, 0, 0);
      }
    }
#pragma unroll
    for (int i = 0; i < 4; ++i) {
      const int m0 = (tm << 7) + wm + (i << 4) + (q4 << 2);
      const int b = m0 >> 12, row0 = m0 & 4095;
#pragma unroll
      for (int j = 0; j < 4; ++j) {
        const int dd = wn + (j << 4) + m15;
        const long bh = b * 8 + h;
        uint2 u;
        u.x = pkbf2(acc[i][j][0], acc[i][j][1]);
        u.y = pkbf2(acc[i][j][2], acc[i][j][3]);
        *(uint2*)&Vt[(bh * 128 + dd) * 4096 + row0] = u;
      }
    }
  } else {
    for (int kb = 0; kb < 1024; kb += 64) {
      __syncthreads();
      QKV_STAGE();
      __syncthreads();
#pragma unroll
      for (int kk = 0; kk < 2; ++kk) {
        short8 afr[4], bfr[4];
#pragma unroll
        for (int i = 0; i < 4; ++i)
          afr[i] = *(const short8*)&lA[kk * 4 + q4][wm + i * 16 + m15][0];
#pragma unroll
        for (int j = 0; j < 4; ++j)
          bfr[j] = *(const short8*)&lB[kk * 4 + q4][wn + j * 16 + m15][0];
#pragma unroll
        for (int i = 0; i < 4; ++i)
#pragma unroll
          for (int j = 0; j < 4; ++j)
            acc[i][j] = __builtin_amdgcn_mfma_f32_16x16x32_bf16(
                bfr[j], afr[i], acc[i][j], 0, 0, 0);
      }
    }
    unsigned short* Dst = (which == 0) ? Qs : Ks;
    const float sc = (which == 0) ? SCALE_Q : 1.0f;
#pragma unroll
    for (int i = 0; i < 4; ++i) {
      const int m = (tm << 7) + wm + (i << 4) + m15;
      const int b = m >> 12, row = m & 4095;
      const long bh = b * 8 + h;
#pragma unroll
      for (int j = 0; j < 4; ++j) {
        const int dd0 = wn + (j << 4) + (q4 << 2);
        uint2 u;
        u.x = pkbf2(acc[i][j][0] * sc, acc[i][j][1] * sc);
        u.y = pkbf2(acc[i][j][2] * sc, acc[i][j][3] * sc);
        *(uint2*)&Dst[(bh * 4096 + row) * 128 + dd0] = u;
      }
    }
  }
#undef QKV_STAGE
}

// ---------------- flash attention ----------------
// 4 waves x 32 q-rows = 128 rows/block; 512 blocks; 2 blocks/CU (LDS 64KB).
// 32x32x16 MFMA; in-register P exchange via v_permlane32_swap_b32.
__global__ __launch_bounds__(256, 2) void k_flash(
    const unsigned short* __restrict__ Qs, const unsigned short* __restrict__ Ks,
    const unsigned short* __restrict__ Vt,
    const unsigned long long* __restrict__ mbits,
    unsigned short* __restrict__ Ob) {
  __shared__ __align__(16) unsigned short lK[2][16][64][8];   // 2 x 16 KB
  __shared__ __align__(16) unsigned short lV[2][8][128][8];   // 2 x 16 KB

  const int tid = threadIdx.x;
  const int w = tid >> 6, ln = tid & 63;
  const int l31 = ln & 31, hi = ln >> 5, hi4 = hi << 2;
  const bool hib = hi != 0;
  (void)hib;
  const int id = blockIdx.x;
  const int xcd = id & 7, jj = id >> 3;           // 64 blocks per XCD
  const int bh = (xcd << 1) | (jj >> 5);          // 2 bh per XCD (4MB K/V in L2)
  const int rowblk = jj & 31;
  const int rbase = rowblk * 128 + w * 32;
  const int qrow = rbase + l31;

  const unsigned short* Qbh = Qs + (long)bh * 524288;
  const unsigned short* Kbh = Ks + (long)bh * 524288;
  const unsigned short* Vbh = Vt + (long)bh * 524288;

  // Q as B-frag of mfma32(K, Q): lane(col=q=l31, hi) holds k = hi*8+e per step
  short8 qf[8];
#pragma unroll
  for (int ks = 0; ks < 8; ++ks)
    qf[ks] = *(const short8*)(Qbh + (long)qrow * 128 + ks * 16 + hi * 8);

  f32x16 o[4];
#pragma unroll
  for (int d = 0; d < 4; ++d)
#pragma unroll
    for (int r = 0; r < 16; ++r) o[d][r] = 0.f;
  float lacc = 0.f;

  const bool maskblk = rowblk < 16;   // rows 0..2047

#define STAGE_KV(dst, kvoff)                                              \
  {                                                                       \
    _Pragma("unroll")                                                     \
    for (int c = 0; c < 4; ++c) {                                         \
      const int p = ((c * 4 + w) << 10) + (ln << 4);                      \
      const int cs = p >> 10;                                             \
      const int j = (p & 1023) >> 4;                                      \
      gload_lds16(Kbh + (long)((kvoff) + j) * 128 + cs * 8,               \
                  (char*)&lK[dst][0][0][0] + p);                          \
    }                                                                     \
    _Pragma("unroll")                                                     \
    for (int c = 0; c < 4; ++c) {                                         \
      const int p = ((c * 4 + w) << 10) + (ln << 4);                      \
      const int cv = p >> 11;                                             \
      const int dv = (p & 2047) >> 4;                                     \
      gload_lds16(Vbh + (long)dv * 4096 + (kvoff) + cv * 8,               \
                  (char*)&lV[dst][0][0][0] + p);                          \
    }                                                                     \
  }

  // half-exchange across lane<32/lane>=32: newA=(loA,loB), newB=(hiA,hiB)
#if __has_builtin(__builtin_amdgcn_permlane32_swap)
#define PLSWAP(a, b)                                                      \
  {                                                                       \
    uint2v r_ = __builtin_amdgcn_permlane32_swap((a), (b), false, false); \
    (a) = r_[0]; (b) = r_[1];                                             \
  }
#else
#define PLSWAP(a, b)                                                      \
  {                                                                       \
    const unsigned pa_ = (unsigned)__shfl_xor((int)(a), 32);              \
    const unsigned pb_ = (unsigned)__shfl_xor((int)(b), 32);              \
    const unsigned na_ = hib ? pb_ : (a);                                 \
    const unsigned nb_ = hib ? (b) : pa_;                                 \
    (a) = na_; (b) = nb_;                                                 \
  }
#endif

  STAGE_KV(0, 0);
  __syncthreads();

  int cur = 0;
  for (int kv = 0; kv < 4096; kv += 64) {
    unsigned long long mw = 0ull;
    const bool domask = maskblk && (kv < 2048);
    if (domask) mw = mbits[(long)qrow * 32 + (kv >> 6)];

    const int nb = cur ^ 1;
    if (kv + 64 < 4096) STAGE_KV(nb, kv + 64);

    // S^T tiles: s0 = kv[0..31], s1 = kv[32..63]; col=q=l31,
    // row(kv_local) = (r&3) + 8*(r>>2) + 4*hi
    f32x16 s0, s1;
#pragma unroll
    for (int r = 0; r < 16; ++r) { s0[r] = 0.f; s1[r] = 0.f; }
    __builtin_amdgcn_s_setprio(1);
#pragma unroll
    for (int ks = 0; ks < 8; ++ks) {
      const short8 kf0 = *(const short8*)&lK[cur][ks * 2 + hi][l31][0];
      const short8 kf1 = *(const short8*)&lK[cur][ks * 2 + hi][32 + l31][0];
      s0 = __builtin_amdgcn_mfma_f32_32x32x16_bf16(kf0, qf[ks], s0, 0, 0, 0);
      s1 = __builtin_amdgcn_mfma_f32_32x32x16_bf16(kf1, qf[ks], s1, 0, 0, 0);
    }
    __builtin_amdgcn_s_setprio(0);

    if (domask) {
      const unsigned mlo = ((unsigned)mw) >> hi4;
      const unsigned mhi = ((unsigned)(mw >> 32)) >> hi4;
#pragma unroll
      for (int r = 0; r < 16; ++r) {
        const int c = ((r >> 2) << 3) + (r & 3);
        if (!((mlo >> c) & 1u)) s0[r] = -1e30f;
        if (!((mhi >> c) & 1u)) s1[r] = -1e30f;
      }
    }

    // p = exp2(s); rowsum partial (union over hi-halves covers all 64 kv)
    float p0[16], p1[16];
#pragma unroll
    for (int r = 0; r < 16; ++r) {
      p0[r] = __builtin_amdgcn_exp2f(s0[r]);
      p1[r] = __builtin_amdgcn_exp2f(s1[r]);
      lacc += p0[r] + p1[r];
    }

    // pack to bf16 + half-swap -> PV A-frags (k = hi*8+e per 16-kv step)
    unsigned w00 = pkbf2(p0[0], p0[1]),   w01 = pkbf2(p0[2], p0[3]);
    unsigned w10 = pkbf2(p0[4], p0[5]),   w11 = pkbf2(p0[6], p0[7]);
    PLSWAP(w00, w10); PLSWAP(w01, w11);
    unsigned w20 = pkbf2(p0[8], p0[9]),   w21 = pkbf2(p0[10], p0[11]);
    unsigned w30 = pkbf2(p0[12], p0[13]), w31 = pkbf2(p0[14], p0[15]);
    PLSWAP(w20, w30); PLSWAP(w21, w31);
    unsigned x00 = pkbf2(p1[0], p1[1]),   x01 = pkbf2(p1[2], p1[3]);
    unsigned x10 = pkbf2(p1[4], p1[5]),   x11 = pkbf2(p1[6], p1[7]);
    PLSWAP(x00, x10); PLSWAP(x01, x11);
    unsigned x20 = pkbf2(p1[8], p1[9]),   x21 = pkbf2(p1[10], p1[11]);
    unsigned x30 = pkbf2(p1[12], p1[13]), x31 = pkbf2(p1[14], p1[15]);
    PLSWAP(x20, x30); PLSWAP(x21, x31);

    union { unsigned u[4]; short8 s; } pa0, pa1, pa2, pa3;
    pa0.u[0] = w00; pa0.u[1] = w01; pa0.u[2] = w10; pa0.u[3] = w11;
    pa1.u[0] = w20; pa1.u[1] = w21; pa1.u[2] = w30; pa1.u[3] = w31;
    pa2.u[0] = x00; pa2.u[1] = x01; pa2.u[2] = x10; pa2.u[3] = x11;
    pa3.u[0] = x20; pa3.u[1] = x21; pa3.u[2] = x30; pa3.u[3] = x31;
    const short8 pa[4] = {pa0.s, pa1.s, pa2.s, pa3.s};

    // O += P @ V  : B-frag lane(col=d=l31, hi) holds V[kv=hi*8+e][d]
    __builtin_amdgcn_s_setprio(1);
#pragma unroll
    for (int ksl = 0; ksl < 4; ++ksl) {
#pragma unroll
      for (int db = 0; db < 4; ++db) {
        const short8 vf =
            *(const short8*)&lV[cur][ksl * 2 + hi][db * 32 + l31][0];
        o[db] = __builtin_amdgcn_mfma_f32_32x32x16_bf16(pa[ksl], vf,
                                                        o[db], 0, 0, 0);
      }
    }
    __builtin_amdgcn_s_setprio(0);

    __syncthreads();
    cur = nb;
  }
#undef STAGE_KV
#undef PLSWAP

  // l[q] = own half + partner half; linv lives at lane q (both halves)
  const float lh = lacc + __shfl_xor(lacc, 32);
  const float linv = 1.0f / lh;

  const int b = bh >> 3, h = bh & 7;
#pragma unroll
  for (int r = 0; r < 16; ++r) {
    const int qr = (r & 3) + ((r >> 2) << 3) + hi4;
    const float li = __shfl(linv, qr);
    const int row = rbase + qr;
    unsigned short* op = Ob + ((long)(b * 4096 + row)) * 1024 + h * 128 + l31;
#pragma unroll
    for (int db = 0; db < 4; ++db)
      op[db * 32] = f2bf(o[db][r] * li);
  }
}

// ---------------- out projection (BK=64) ----------------
__global__ __launch_bounds__(256, 2) void k_proj_gemm(
    const unsigned short* __restrict__ A,   // [8192][1024]
    const unsigned short* __restrict__ Bt,  // [1024][1024]
    const float* __restrict__ bias, float* __restrict__ Out) {
  __shared__ __align__(16) unsigned short lA[8][128][8];
  __shared__ __align__(16) unsigned short lB[8][128][8];
  const int tid = threadIdx.x;
  const int w = tid >> 6, ln = tid & 63;
  const int m15 = ln & 15, q4 = ln >> 4;
  const int wm = (w >> 1) << 6, wn = (w & 1) << 6;
  const int id = blockIdx.x;
  const int swz = (id & 7) * 64 + (id >> 3);
  const int tn = swz & 7, tm = swz >> 3;

  f32x4 acc[4][4];
#pragma unroll
  for (int i = 0; i < 4; ++i)
#pragma unroll
    for (int j = 0; j < 4; ++j) acc[i][j] = zero4();

  for (int kb = 0; kb < 1024; kb += 64) {
    __syncthreads();
#pragma unroll
    for (int c = 0; c < 4; ++c) {
      const int p = ((c * 4 + w) << 10) + (ln << 4);
      const int g = p >> 11;
      const int r = (p & 2047) >> 4;
      gload_lds16(A + ((long)tm * 128 + r) * 1024 + kb + g * 8,
                  (char*)&lA[0][0][0] + p);
      gload_lds16(Bt + ((long)tn * 128 + r) * 1024 + kb + g * 8,
                  (char*)&lB[0][0][0] + p);
    }
    __syncthreads();
#pragma unroll
    for (int kk = 0; kk < 2; ++kk) {
      short8 afr[4], bfr[4];
#pragma unroll
      for (int i = 0; i < 4; ++i)
        afr[i] = *(const short8*)&lA[kk * 4 + q4][wm + i * 16 + m15][0];
#pragma unroll
      for (int j = 0; j < 4; ++j)
        bfr[j] = *(const short8*)&lB[kk * 4 + q4][wn + j * 16 + m15][0];
#pragma unroll
      for (int i = 0; i < 4; ++i)
#pragma unroll
        for (int j = 0; j < 4; ++j)
          acc[i][j] = __builtin_amdgcn_mfma_f32_16x16x32_bf16(
              afr[i], bfr[j], acc[i][j], 0, 0, 0);
    }
  }

#pragma unroll
  for (int i = 0; i < 4; ++i)
#pragma unroll
    for (int r = 0; r < 4; ++r) {
      const int m = (tm << 7) + wm + (i << 4) + (q4 << 2) + r;
#pragma unroll
      for (int j = 0; j < 4; ++j) {
        const int n = (tn << 7) + wn + (j << 4) + m15;
        Out[(long)m * 1024 + n] = acc[i][j][r] + bias[n];
      }
    }
}

extern "C" void kernel_launch(void* const* d_in, const int* in_sizes, int n_in,
                              void* d_out, int out_size, void* d_ws,
                              size_t ws_size, hipStream_t stream) {
  const float* x = (const float*)d_in[0];
  const float* Wqkv = (const float*)d_in[1];
  const float* Wout = (const float*)d_in[2];
  const float* bout = (const float*)d_in[3];
  const int* mask = (const int*)d_in[4];
  float* out = (float*)d_out;

  char* ws = (char*)d_ws;
  unsigned short* xb     = (unsigned short*)(ws);            // later Ob
  unsigned short* wqkv_t = (unsigned short*)(ws + 16777216);
  unsigned short* wout_t = (unsigned short*)(ws + 23068672);
  unsigned short* Qs     = (unsigned short*)(ws + 25165824);
  unsigned short* Ks     = (unsigned short*)(ws + 41943040);
  unsigned short* Vt     = (unsigned short*)(ws + 58720256);
  unsigned short* Ob     = xb;                         // xb dead after qkv
  unsigned long long* mbits = (unsigned long long*)wqkv_t;  // wqkv_t dead after qkv

  hipLaunchKernelGGL(k_cvt_x, dim3(8192), dim3(256), 0, stream, x, xb);
  hipLaunchKernelGGL(k_cvt_wt, dim3(96, 32), dim3(256), 0, stream, Wqkv, wqkv_t, 3072);
  hipLaunchKernelGGL(k_cvt_wt, dim3(32, 32), dim3(256), 0, stream, Wout, wout_t, 1024);
  hipLaunchKernelGGL(k_qkv_gemm, dim3(1536), dim3(256), 0, stream,
                     xb, wqkv_t, Qs, Ks, Vt);
  hipLaunchKernelGGL(k_mask_bits, dim3(16384), dim3(256), 0, stream,
                     mask, mbits);
  hipLaunchKernelGGL(k_flash, dim3(512), dim3(256), 0, stream,
                     Qs, Ks, Vt, mbits, Ob);
  hipLaunchKernelGGL(k_proj_gemm, dim3(512), dim3(256), 0, stream,
                     Ob, wout_t, bout, out);
}

// Round 8
// 426.200 us; speedup vs baseline: 1.0118x; 1.0118x over previous
//
#include <hip/hip_runtime.h>
#include <hip/hip_bf16.h>
#include <stdint.h>

// Round 14 = round 13 with the aliasing bug fixed.
// BUG (round 13): mbits aliases wqkv_t ("dead after qkv"); fusing the mask
// pack into k_prep made it run BEFORE k_qkv_gemm -> overwrote 512KB of
// converted weights -> exp2 overflow -> NaN. FIX: k_mask_bits is again a
// separate launch AFTER k_qkv_gemm (round-12 position).
// Kept from round 13:
//  1) qkv/proj GEMMs: 2-phase double-buffer (prefetch t+1 during compute t,
//     one barrier/step). LDS 64KB, 2 blocks/CU.
//  2) k_prep fuses cvt_x + both cvt_wt (targets not aliased).
//  3) flash split-half QK|SM0|PV0|SM1|PV1.
// Carried: 32x32x16 flash + permlane32_swap P (bank-conflict 0), 2 blk/CU,
// XCD-pinned grids (FETCH 26.7MB), bitmask mask, exp2 softmax.
//
// ws layout:
//   xb      [8192][1024] bf16  @ 0         (dead after qkv -> Ob)
//   wqkv_t  [3072][1024] bf16  @ 16777216  (dead after qkv -> mbits)
//   wout_t  [1024][1024] bf16  @ 23068672
//   Qs      [16][4096][128]    @ 25165824
//   Ks      [16][4096][128]    @ 41943040
//   Vt      [16][128][4096]    @ 58720256

typedef __attribute__((ext_vector_type(8))) short short8;
typedef __attribute__((ext_vector_type(4))) float f32x4;
typedef __attribute__((ext_vector_type(16))) float f32x16;
typedef unsigned int uint2v __attribute__((ext_vector_type(2)));

// DIM^-0.5 * log2(e): S computed in log2 domain, exp via exp2.
#define SCALE_Q 0.0450842200f

__device__ __forceinline__ unsigned short f2bf(float f) {
  union { float f; unsigned int u; } v;
  v.f = f;
  return (unsigned short)((v.u + 0x7fffu + ((v.u >> 16) & 1u)) >> 16);
}

__device__ __forceinline__ unsigned int pkbf2(float a, float b) {
  __hip_bfloat162 h = __float22bfloat162_rn(make_float2(a, b));
  union { __hip_bfloat162 h; unsigned int u; } c;
  c.h = h;
  return c.u;
}

__device__ __forceinline__ void gload_lds16(const void* g, void* l) {
  __builtin_amdgcn_global_load_lds(
      (const __attribute__((address_space(1))) uint32_t*)(uintptr_t)g,
      (__attribute__((address_space(3))) uint32_t*)(uintptr_t)l, 16, 0, 0);
}

__device__ __forceinline__ f32x4 zero4() {
  f32x4 z; z.x = 0.f; z.y = 0.f; z.z = 0.f; z.w = 0.f; return z;
}

// ---------------- fused prep: cvt_x | cvt_wt(Wqkv) | cvt_wt(Wout) ----------
__global__ __launch_bounds__(256) void k_prep(
    const float* __restrict__ x, unsigned short* __restrict__ xb,
    const float* __restrict__ Wqkv, unsigned short* __restrict__ wqkv_t,
    const float* __restrict__ Wout, unsigned short* __restrict__ wout_t) {
  __shared__ float t[32][33];
  const int id = blockIdx.x;
  const int tid = threadIdx.x;
  if (id < 8192) {
    // ---- x f32 -> bf16 (vectorized) ----
    const int i = id * 256 + tid;
    const float4 v = ((const float4*)x)[i];
    ushort4 o;
    o.x = f2bf(v.x); o.y = f2bf(v.y); o.z = f2bf(v.z); o.w = f2bf(v.w);
    ((ushort4*)xb)[i] = o;
  } else {
    // ---- weight transpose+convert ----
    const float* w;
    unsigned short* wt;
    int Nn, bx, by;
    if (id < 11264) {
      const int r = id - 8192;            // 3072 blocks (96 x 32)
      w = Wqkv; wt = wqkv_t; Nn = 3072; bx = r % 96; by = r / 96;
    } else {
      const int r = id - 11264;           // 1024 blocks (32 x 32)
      w = Wout; wt = wout_t; Nn = 1024; bx = r % 32; by = r / 32;
    }
    const int n0 = bx << 5, k0 = by << 5;
    const int c = tid & 31, r8 = tid >> 5;
#pragma unroll
    for (int i = 0; i < 4; ++i) {
      const int r = (i << 3) + r8;
      t[r][c] = w[(long)(k0 + r) * Nn + n0 + c];
    }
    __syncthreads();
#pragma unroll
    for (int i = 0; i < 4; ++i) {
      const int r = (i << 3) + r8;
      wt[(long)(n0 + r) * 1024 + k0 + c] = f2bf(t[c][r]);
    }
  }
}

// ---------------- mask -> bitmask (AFTER qkv_gemm: mbits aliases wqkv_t) ----
__global__ __launch_bounds__(256) void k_mask_bits(
    const int* __restrict__ m, unsigned long long* __restrict__ mb) {
  const int t = blockIdx.x * 256 + threadIdx.x;
  const unsigned long long b = __ballot(m[t] != 0);
  if ((threadIdx.x & 63) == 0) mb[t >> 6] = b;
}

// ---------------- QKV GEMM (BK=64, 2-phase dbuf) ----------------
__global__ __launch_bounds__(256, 2) void k_qkv_gemm(
    const unsigned short* __restrict__ A,   // [8192][1024]
    const unsigned short* __restrict__ Bt,  // [3072][1024]
    unsigned short* __restrict__ Qs, unsigned short* __restrict__ Ks,
    unsigned short* __restrict__ Vt) {
  __shared__ __align__(16) unsigned short lA[2][8][128][8];   // 2 x 16 KB
  __shared__ __align__(16) unsigned short lB[2][8][128][8];   // 2 x 16 KB
  const int tid = threadIdx.x;
  const int w = tid >> 6, ln = tid & 63;
  const int m15 = ln & 15, q4 = ln >> 4;
  const int wm = (w >> 1) << 6, wn = (w & 1) << 6;
  const int id = blockIdx.x;
  const int swz = (id & 7) * 192 + (id >> 3);   // XCD-chunked remap
  const int tn = swz % 24, tm = swz / 24;
  const int which = tn >> 3;   // 0=Q 1=K 2=V (uniform per block)
  const int h = tn & 7;

  f32x4 acc[4][4];
#pragma unroll
  for (int i = 0; i < 4; ++i)
#pragma unroll
    for (int j = 0; j < 4; ++j) acc[i][j] = zero4();

#define QKV_STAGE(buf, kb)                                                \
  {                                                                       \
    _Pragma("unroll")                                                     \
    for (int c = 0; c < 4; ++c) {                                         \
      const int p = ((c * 4 + w) << 10) + (ln << 4);                      \
      const int g = p >> 11;                                              \
      const int r = (p & 2047) >> 4;                                      \
      gload_lds16(A + ((long)tm * 128 + r) * 1024 + (kb) + g * 8,         \
                  (char*)&lA[buf][0][0][0] + p);                          \
      gload_lds16(Bt + ((long)tn * 128 + r) * 1024 + (kb) + g * 8,        \
                  (char*)&lB[buf][0][0][0] + p);                          \
    }                                                                     \
  }

  QKV_STAGE(0, 0);
  __syncthreads();

  int cur = 0;
  if (which == 2) {
    for (int kb = 0; kb < 1024; kb += 64) {
      const int nb2 = cur ^ 1;
      if (kb + 64 < 1024) QKV_STAGE(nb2, kb + 64);
#pragma unroll
      for (int kk = 0; kk < 2; ++kk) {
        short8 afr[4], bfr[4];
#pragma unroll
        for (int i = 0; i < 4; ++i)
          afr[i] = *(const short8*)&lA[cur][kk * 4 + q4][wm + i * 16 + m15][0];
#pragma unroll
        for (int j = 0; j < 4; ++j)
          bfr[j] = *(const short8*)&lB[cur][kk * 4 + q4][wn + j * 16 + m15][0];
#pragma unroll
        for (int i = 0; i < 4; ++i)
#pragma unroll
          for (int j = 0; j < 4; ++j)
            acc[i][j] = __builtin_amdgcn_mfma_f32_16x16x32_bf16(
                afr[i], bfr[j], acc[i][j], 0, 0, 0);
      }
      __syncthreads();
      cur = nb2;
    }
#pragma unroll
    for (int i = 0; i < 4; ++i) {
      const int m0 = (tm << 7) + wm + (i << 4) + (q4 << 2);
      const int b = m0 >> 12, row0 = m0 & 4095;
#pragma unroll
      for (int j = 0; j < 4; ++j) {
        const int dd = wn + (j << 4) + m15;
        const long bh = b * 8 + h;
        uint2 u;
        u.x = pkbf2(acc[i][j][0], acc[i][j][1]);
        u.y = pkbf2(acc[i][j][2], acc[i][j][3]);
        *(uint2*)&Vt[(bh * 128 + dd) * 4096 + row0] = u;
      }
    }
  } else {
    for (int kb = 0; kb < 1024; kb += 64) {
      const int nb2 = cur ^ 1;
      if (kb + 64 < 1024) QKV_STAGE(nb2, kb + 64);
#pragma unroll
      for (int kk = 0; kk < 2; ++kk) {
        short8 afr[4], bfr[4];
#pragma unroll
        for (int i = 0; i < 4; ++i)
          afr[i] = *(const short8*)&lA[cur][kk * 4 + q4][wm + i * 16 + m15][0];
#pragma unroll
        for (int j = 0; j < 4; ++j)
          bfr[j] = *(const short8*)&lB[cur][kk * 4 + q4][wn + j * 16 + m15][0];
#pragma unroll
        for (int i = 0; i < 4; ++i)
#pragma unroll
          for (int j = 0; j < 4; ++j)
            acc[i][j] = __builtin_amdgcn_mfma_f32_16x16x32_bf16(
                bfr[j], afr[i], acc[i][j], 0, 0, 0);
      }
      __syncthreads();
      cur = nb2;
    }
    unsigned short* Dst = (which == 0) ? Qs : Ks;
    const float sc = (which == 0) ? SCALE_Q : 1.0f;
#pragma unroll
    for (int i = 0; i < 4; ++i) {
      const int m = (tm << 7) + wm + (i << 4) + m15;
      const int b = m >> 12, row = m & 4095;
      const long bh = b * 8 + h;
#pragma unroll
      for (int j = 0; j < 4; ++j) {
        const int dd0 = wn + (j << 4) + (q4 << 2);
        uint2 u;
        u.x = pkbf2(acc[i][j][0] * sc, acc[i][j][1] * sc);
        u.y = pkbf2(acc[i][j][2] * sc, acc[i][j][3] * sc);
        *(uint2*)&Dst[(bh * 4096 + row) * 128 + dd0] = u;
      }
    }
  }
#undef QKV_STAGE
}

// ---------------- flash attention ----------------
// 4 waves x 32 q-rows = 128 rows/block; 512 blocks; 2 blocks/CU (LDS 64KB).
// 32x32x16 MFMA; in-register P via permlane32_swap; split-half SM/PV.
__global__ __launch_bounds__(256, 2) void k_flash(
    const unsigned short* __restrict__ Qs, const unsigned short* __restrict__ Ks,
    const unsigned short* __restrict__ Vt,
    const unsigned long long* __restrict__ mbits,
    unsigned short* __restrict__ Ob) {
  __shared__ __align__(16) unsigned short lK[2][16][64][8];   // 2 x 16 KB
  __shared__ __align__(16) unsigned short lV[2][8][128][8];   // 2 x 16 KB

  const int tid = threadIdx.x;
  const int w = tid >> 6, ln = tid & 63;
  const int l31 = ln & 31, hi = ln >> 5, hi4 = hi << 2;
  const bool hib = hi != 0;
  (void)hib;
  const int id = blockIdx.x;
  const int xcd = id & 7, jj = id >> 3;           // 64 blocks per XCD
  const int bh = (xcd << 1) | (jj >> 5);          // 2 bh per XCD (4MB K/V in L2)
  const int rowblk = jj & 31;
  const int rbase = rowblk * 128 + w * 32;
  const int qrow = rbase + l31;

  const unsigned short* Qbh = Qs + (long)bh * 524288;
  const unsigned short* Kbh = Ks + (long)bh * 524288;
  const unsigned short* Vbh = Vt + (long)bh * 524288;

  // Q as B-frag of mfma32(K, Q): lane(col=q=l31, hi) holds k = hi*8+e per step
  short8 qf[8];
#pragma unroll
  for (int ks = 0; ks < 8; ++ks)
    qf[ks] = *(const short8*)(Qbh + (long)qrow * 128 + ks * 16 + hi * 8);

  f32x16 o[4];
#pragma unroll
  for (int d = 0; d < 4; ++d)
#pragma unroll
    for (int r = 0; r < 16; ++r) o[d][r] = 0.f;
  float lacc = 0.f;

  const bool maskblk = rowblk < 16;   // rows 0..2047

#define STAGE_KV(dst, kvoff)                                              \
  {                                                                       \
    _Pragma("unroll")                                                     \
    for (int c = 0; c < 4; ++c) {                                         \
      const int p = ((c * 4 + w) << 10) + (ln << 4);                      \
      const int cs = p >> 10;                                             \
      const int j = (p & 1023) >> 4;                                      \
      gload_lds16(Kbh + (long)((kvoff) + j) * 128 + cs * 8,               \
                  (char*)&lK[dst][0][0][0] + p);                          \
    }                                                                     \
    _Pragma("unroll")                                                     \
    for (int c = 0; c < 4; ++c) {                                         \
      const int p = ((c * 4 + w) << 10) + (ln << 4);                      \
      const int cv = p >> 11;                                             \
      const int dv = (p & 2047) >> 4;                                     \
      gload_lds16(Vbh + (long)dv * 4096 + (kvoff) + cv * 8,               \
                  (char*)&lV[dst][0][0][0] + p);                          \
    }                                                                     \
  }

  // half-exchange across lane<32/lane>=32: newA=(loA,loB), newB=(hiA,hiB)
#if __has_builtin(__builtin_amdgcn_permlane32_swap)
#define PLSWAP(a, b)                                                      \
  {                                                                       \
    uint2v r_ = __builtin_amdgcn_permlane32_swap((a), (b), false, false); \
    (a) = r_[0]; (b) = r_[1];                                             \
  }
#else
#define PLSWAP(a, b)                                                      \
  {                                                                       \
    const unsigned pa_ = (unsigned)__shfl_xor((int)(a), 32);              \
    const unsigned pb_ = (unsigned)__shfl_xor((int)(b), 32);              \
    const unsigned na_ = hib ? pb_ : (a);                                 \
    const unsigned nb_ = hib ? (b) : pa_;                                 \
    (a) = na_; (b) = nb_;                                                 \
  }
#endif

  STAGE_KV(0, 0);
  __syncthreads();

  int cur = 0;
  for (int kv = 0; kv < 4096; kv += 64) {
    unsigned long long mw = 0ull;
    const bool domask = maskblk && (kv < 2048);
    if (domask) mw = mbits[(long)qrow * 32 + (kv >> 6)];

    const int nb = cur ^ 1;
    if (kv + 64 < 4096) STAGE_KV(nb, kv + 64);

    // ---- QK^T both halves: s0 = kv[0..31], s1 = kv[32..63]; col=q=l31,
    // row(kv_local) = (r&3) + 8*(r>>2) + 4*hi
    f32x16 s0, s1;
#pragma unroll
    for (int r = 0; r < 16; ++r) { s0[r] = 0.f; s1[r] = 0.f; }
    __builtin_amdgcn_s_setprio(1);
#pragma unroll
    for (int ks = 0; ks < 8; ++ks) {
      const short8 kf0 = *(const short8*)&lK[cur][ks * 2 + hi][l31][0];
      const short8 kf1 = *(const short8*)&lK[cur][ks * 2 + hi][32 + l31][0];
      s0 = __builtin_amdgcn_mfma_f32_32x32x16_bf16(kf0, qf[ks], s0, 0, 0, 0);
      s1 = __builtin_amdgcn_mfma_f32_32x32x16_bf16(kf1, qf[ks], s1, 0, 0, 0);
    }
    __builtin_amdgcn_s_setprio(0);

    const unsigned mlo = ((unsigned)mw) >> hi4;
    const unsigned mhi = ((unsigned)(mw >> 32)) >> hi4;

    // ---- SM0: mask+exp+pack for kv[0..31] -> pa0, pa1
    if (domask) {
#pragma unroll
      for (int r = 0; r < 16; ++r) {
        const int c = ((r >> 2) << 3) + (r & 3);
        if (!((mlo >> c) & 1u)) s0[r] = -1e30f;
      }
    }
    float p0[16];
#pragma unroll
    for (int r = 0; r < 16; ++r) {
      p0[r] = __builtin_amdgcn_exp2f(s0[r]);
      lacc += p0[r];
    }
    unsigned w00 = pkbf2(p0[0], p0[1]),   w01 = pkbf2(p0[2], p0[3]);
    unsigned w10 = pkbf2(p0[4], p0[5]),   w11 = pkbf2(p0[6], p0[7]);
    PLSWAP(w00, w10); PLSWAP(w01, w11);
    unsigned w20 = pkbf2(p0[8], p0[9]),   w21 = pkbf2(p0[10], p0[11]);
    unsigned w30 = pkbf2(p0[12], p0[13]), w31 = pkbf2(p0[14], p0[15]);
    PLSWAP(w20, w30); PLSWAP(w21, w31);
    union { unsigned u[4]; short8 s; } pa0, pa1;
    pa0.u[0] = w00; pa0.u[1] = w01; pa0.u[2] = w10; pa0.u[3] = w11;
    pa1.u[0] = w20; pa1.u[1] = w21; pa1.u[2] = w30; pa1.u[3] = w31;

    // ---- PV0: kv[0..31] (independent of SM1)
    __builtin_amdgcn_s_setprio(1);
#pragma unroll
    for (int db = 0; db < 4; ++db) {
      const short8 vf0 = *(const short8*)&lV[cur][hi][db * 32 + l31][0];
      o[db] = __builtin_amdgcn_mfma_f32_32x32x16_bf16(pa0.s, vf0, o[db], 0, 0, 0);
      const short8 vf1 = *(const short8*)&lV[cur][2 + hi][db * 32 + l31][0];
      o[db] = __builtin_amdgcn_mfma_f32_32x32x16_bf16(pa1.s, vf1, o[db], 0, 0, 0);
    }
    __builtin_amdgcn_s_setprio(0);

    // ---- SM1: mask+exp+pack for kv[32..63] -> pa2, pa3
    if (domask) {
#pragma unroll
      for (int r = 0; r < 16; ++r) {
        const int c = ((r >> 2) << 3) + (r & 3);
        if (!((mhi >> c) & 1u)) s1[r] = -1e30f;
      }
    }
    float p1[16];
#pragma unroll
    for (int r = 0; r < 16; ++r) {
      p1[r] = __builtin_amdgcn_exp2f(s1[r]);
      lacc += p1[r];
    }
    unsigned x00 = pkbf2(p1[0], p1[1]),   x01 = pkbf2(p1[2], p1[3]);
    unsigned x10 = pkbf2(p1[4], p1[5]),   x11 = pkbf2(p1[6], p1[7]);
    PLSWAP(x00, x10); PLSWAP(x01, x11);
    unsigned x20 = pkbf2(p1[8], p1[9]),   x21 = pkbf2(p1[10], p1[11]);
    unsigned x30 = pkbf2(p1[12], p1[13]), x31 = pkbf2(p1[14], p1[15]);
    PLSWAP(x20, x30); PLSWAP(x21, x31);
    union { unsigned u[4]; short8 s; } pa2, pa3;
    pa2.u[0] = x00; pa2.u[1] = x01; pa2.u[2] = x10; pa2.u[3] = x11;
    pa3.u[0] = x20; pa3.u[1] = x21; pa3.u[2] = x30; pa3.u[3] = x31;

    // ---- PV1: kv[32..63]
    __builtin_amdgcn_s_setprio(1);
#pragma unroll
    for (int db = 0; db < 4; ++db) {
      const short8 vf2 = *(const short8*)&lV[cur][4 + hi][db * 32 + l31][0];
      o[db] = __builtin_amdgcn_mfma_f32_32x32x16_bf16(pa2.s, vf2, o[db], 0, 0, 0);
      const short8 vf3 = *(const short8*)&lV[cur][6 + hi][db * 32 + l31][0];
      o[db] = __builtin_amdgcn_mfma_f32_32x32x16_bf16(pa3.s, vf3, o[db], 0, 0, 0);
    }
    __builtin_amdgcn_s_setprio(0);

    __syncthreads();
    cur = nb;
  }
#undef STAGE_KV
#undef PLSWAP

  // l[q] = own half + partner half; linv lives at lane q (both halves)
  const float lh = lacc + __shfl_xor(lacc, 32);
  const float linv = 1.0f / lh;

  const int b = bh >> 3, h = bh & 7;
#pragma unroll
  for (int r = 0; r < 16; ++r) {
    const int qr = (r & 3) + ((r >> 2) << 3) + hi4;
    const float li = __shfl(linv, qr);
    const int row = rbase + qr;
    unsigned short* op = Ob + ((long)(b * 4096 + row)) * 1024 + h * 128 + l31;
#pragma unroll
    for (int db = 0; db < 4; ++db)
      op[db * 32] = f2bf(o[db][r] * li);
  }
}

// ---------------- out projection (BK=64, 2-phase dbuf) ----------------
__global__ __launch_bounds__(256, 2) void k_proj_gemm(
    const unsigned short* __restrict__ A,   // [8192][1024]
    const unsigned short* __restrict__ Bt,  // [1024][1024]
    const float* __restrict__ bias, float* __restrict__ Out) {
  __shared__ __align__(16) unsigned short lA[2][8][128][8];
  __shared__ __align__(16) unsigned short lB[2][8][128][8];
  const int tid = threadIdx.x;
  const int w = tid >> 6, ln = tid & 63;
  const int m15 = ln & 15, q4 = ln >> 4;
  const int wm = (w >> 1) << 6, wn = (w & 1) << 6;
  const int id = blockIdx.x;
  const int swz = (id & 7) * 64 + (id >> 3);
  const int tn = swz & 7, tm = swz >> 3;

  f32x4 acc[4][4];
#pragma unroll
  for (int i = 0; i < 4; ++i)
#pragma unroll
    for (int j = 0; j < 4; ++j) acc[i][j] = zero4();

#define PROJ_STAGE(buf, kb)                                               \
  {                                                                       \
    _Pragma("unroll")                                                     \
    for (int c = 0; c < 4; ++c) {                                         \
      const int p = ((c * 4 + w) << 10) + (ln << 4);                      \
      const int g = p >> 11;                                              \
      const int r = (p & 2047) >> 4;                                      \
      gload_lds16(A + ((long)tm * 128 + r) * 1024 + (kb) + g * 8,         \
                  (char*)&lA[buf][0][0][0] + p);                          \
      gload_lds16(Bt + ((long)tn * 128 + r) * 1024 + (kb) + g * 8,        \
                  (char*)&lB[buf][0][0][0] + p);                          \
    }                                                                     \
  }

  PROJ_STAGE(0, 0);
  __syncthreads();

  int cur = 0;
  for (int kb = 0; kb < 1024; kb += 64) {
    const int nb2 = cur ^ 1;
    if (kb + 64 < 1024) PROJ_STAGE(nb2, kb + 64);
#pragma unroll
    for (int kk = 0; kk < 2; ++kk) {
      short8 afr[4], bfr[4];
#pragma unroll
      for (int i = 0; i < 4; ++i)
        afr[i] = *(const short8*)&lA[cur][kk * 4 + q4][wm + i * 16 + m15][0];
#pragma unroll
      for (int j = 0; j < 4; ++j)
        bfr[j] = *(const short8*)&lB[cur][kk * 4 + q4][wn + j * 16 + m15][0];
#pragma unroll
      for (int i = 0; i < 4; ++i)
#pragma unroll
        for (int j = 0; j < 4; ++j)
          acc[i][j] = __builtin_amdgcn_mfma_f32_16x16x32_bf16(
              afr[i], bfr[j], acc[i][j], 0, 0, 0);
    }
    __syncthreads();
    cur = nb2;
  }
#undef PROJ_STAGE

#pragma unroll
  for (int i = 0; i < 4; ++i)
#pragma unroll
    for (int r = 0; r < 4; ++r) {
      const int m = (tm << 7) + wm + (i << 4) + (q4 << 2) + r;
#pragma unroll
      for (int j = 0; j < 4; ++j) {
        const int n = (tn << 7) + wn + (j << 4) + m15;
        Out[(long)m * 1024 + n] = acc[i][j][r] + bias[n];
      }
    }
}

extern "C" void kernel_launch(void* const* d_in, const int* in_sizes, int n_in,
                              void* d_out, int out_size, void* d_ws,
                              size_t ws_size, hipStream_t stream) {
  const float* x = (const float*)d_in[0];
  const float* Wqkv = (const float*)d_in[1];
  const float* Wout = (const float*)d_in[2];
  const float* bout = (const float*)d_in[3];
  const int* mask = (const int*)d_in[4];
  float* out = (float*)d_out;

  char* ws = (char*)d_ws;
  unsigned short* xb     = (unsigned short*)(ws);            // later Ob
  unsigned short* wqkv_t = (unsigned short*)(ws + 16777216);
  unsigned short* wout_t = (unsigned short*)(ws + 23068672);
  unsigned short* Qs     = (unsigned short*)(ws + 25165824);
  unsigned short* Ks     = (unsigned short*)(ws + 41943040);
  unsigned short* Vt     = (unsigned short*)(ws + 58720256);
  unsigned short* Ob     = xb;                         // xb dead after qkv
  unsigned long long* mbits = (unsigned long long*)wqkv_t;  // wqkv_t dead after qkv

  hipLaunchKernelGGL(k_prep, dim3(12288), dim3(256), 0, stream,
                     x, xb, Wqkv, wqkv_t, Wout, wout_t);
  hipLaunchKernelGGL(k_qkv_gemm, dim3(1536), dim3(256), 0, stream,
                     xb, wqkv_t, Qs, Ks, Vt);
  hipLaunchKernelGGL(k_mask_bits, dim3(16384), dim3(256), 0, stream,
                     mask, mbits);
  hipLaunchKernelGGL(k_flash, dim3(512), dim3(256), 0, stream,
                     Qs, Ks, Vt, mbits, Ob);
  hipLaunchKernelGGL(k_proj_gemm, dim3(512), dim3(256), 0, stream,
                     Ob, wout_t, bout, out);
}

// Round 9
// 418.076 us; speedup vs baseline: 1.0315x; 1.0194x over previous
//
#include <hip/hip_runtime.h>
#include <hip/hip_bf16.h>
#include <stdint.h>

// Round 15: coalesced LDS-transposed GEMM epilogues.
// Non-flash = 253.7us vs ~115us roofline -> suspect: scattered narrow
// epilogue stores (qkv Q/K: 8B @ 256B stride x16/thread; Vt: 8B @ 8KB
// stride; proj: 4B x16/thread). Each block's output is a contiguous
// [128][128] panel, so: acc -> (dead) staging LDS (XOR-swizzled, padded)
// -> barrier -> row-contiguous 16B reads -> dwordx4 global stores.
// proj folds bias into the read-back pass. Flash untouched (172.5us,
// ~800 TF = plain-HIP attn plateau).
// Carried: 2-phase dbuf GEMMs, k_prep fusion, mask_bits AFTER qkv
// (mbits aliases wqkv_t!), 32x32 flash + permlane P, XCD-pinned grids.
//
// ws layout:
//   xb      [8192][1024] bf16  @ 0         (dead after qkv -> Ob)
//   wqkv_t  [3072][1024] bf16  @ 16777216  (dead after qkv -> mbits)
//   wout_t  [1024][1024] bf16  @ 23068672
//   Qs      [16][4096][128]    @ 25165824
//   Ks      [16][4096][128]    @ 41943040
//   Vt      [16][128][4096]    @ 58720256

typedef __attribute__((ext_vector_type(8))) short short8;
typedef __attribute__((ext_vector_type(4))) float f32x4;
typedef __attribute__((ext_vector_type(16))) float f32x16;
typedef unsigned int uint2v __attribute__((ext_vector_type(2)));

// DIM^-0.5 * log2(e): S computed in log2 domain, exp via exp2.
#define SCALE_Q 0.0450842200f

__device__ __forceinline__ unsigned short f2bf(float f) {
  union { float f; unsigned int u; } v;
  v.f = f;
  return (unsigned short)((v.u + 0x7fffu + ((v.u >> 16) & 1u)) >> 16);
}

__device__ __forceinline__ unsigned int pkbf2(float a, float b) {
  __hip_bfloat162 h = __float22bfloat162_rn(make_float2(a, b));
  union { __hip_bfloat162 h; unsigned int u; } c;
  c.h = h;
  return c.u;
}

__device__ __forceinline__ void gload_lds16(const void* g, void* l) {
  __builtin_amdgcn_global_load_lds(
      (const __attribute__((address_space(1))) uint32_t*)(uintptr_t)g,
      (__attribute__((address_space(3))) uint32_t*)(uintptr_t)l, 16, 0, 0);
}

__device__ __forceinline__ f32x4 zero4() {
  f32x4 z; z.x = 0.f; z.y = 0.f; z.z = 0.f; z.w = 0.f; return z;
}

// ---------------- fused prep: cvt_x | cvt_wt(Wqkv) | cvt_wt(Wout) ----------
__global__ __launch_bounds__(256) void k_prep(
    const float* __restrict__ x, unsigned short* __restrict__ xb,
    const float* __restrict__ Wqkv, unsigned short* __restrict__ wqkv_t,
    const float* __restrict__ Wout, unsigned short* __restrict__ wout_t) {
  __shared__ float t[32][33];
  const int id = blockIdx.x;
  const int tid = threadIdx.x;
  if (id < 8192) {
    const int i = id * 256 + tid;
    const float4 v = ((const float4*)x)[i];
    ushort4 o;
    o.x = f2bf(v.x); o.y = f2bf(v.y); o.z = f2bf(v.z); o.w = f2bf(v.w);
    ((ushort4*)xb)[i] = o;
  } else {
    const float* w;
    unsigned short* wt;
    int Nn, bx, by;
    if (id < 11264) {
      const int r = id - 8192;            // 3072 blocks (96 x 32)
      w = Wqkv; wt = wqkv_t; Nn = 3072; bx = r % 96; by = r / 96;
    } else {
      const int r = id - 11264;           // 1024 blocks (32 x 32)
      w = Wout; wt = wout_t; Nn = 1024; bx = r % 32; by = r / 32;
    }
    const int n0 = bx << 5, k0 = by << 5;
    const int c = tid & 31, r8 = tid >> 5;
#pragma unroll
    for (int i = 0; i < 4; ++i) {
      const int r = (i << 3) + r8;
      t[r][c] = w[(long)(k0 + r) * Nn + n0 + c];
    }
    __syncthreads();
#pragma unroll
    for (int i = 0; i < 4; ++i) {
      const int r = (i << 3) + r8;
      wt[(long)(n0 + r) * 1024 + k0 + c] = f2bf(t[c][r]);
    }
  }
}

// ---------------- mask -> bitmask (AFTER qkv_gemm: mbits aliases wqkv_t) ----
__global__ __launch_bounds__(256) void k_mask_bits(
    const int* __restrict__ m, unsigned long long* __restrict__ mb) {
  const int t = blockIdx.x * 256 + threadIdx.x;
  const unsigned long long b = __ballot(m[t] != 0);
  if ((threadIdx.x & 63) == 0) mb[t >> 6] = b;
}

// ---------------- QKV GEMM (BK=64, 2-phase dbuf, coalesced epilogue) -------
__global__ __launch_bounds__(256, 2) void k_qkv_gemm(
    const unsigned short* __restrict__ A,   // [8192][1024]
    const unsigned short* __restrict__ Bt,  // [3072][1024]
    unsigned short* __restrict__ Qs, unsigned short* __restrict__ Ks,
    unsigned short* __restrict__ Vt) {
  __shared__ __align__(16) unsigned short lsh[2][2][8][128][8];  // 64 KB
  const int tid = threadIdx.x;
  const int w = tid >> 6, ln = tid & 63;
  const int m15 = ln & 15, q4 = ln >> 4;
  const int wm = (w >> 1) << 6, wn = (w & 1) << 6;
  const int id = blockIdx.x;
  const int swz = (id & 7) * 192 + (id >> 3);   // XCD-chunked remap
  const int tn = swz % 24, tm = swz / 24;
  const int which = tn >> 3;   // 0=Q 1=K 2=V (uniform per block)
  const int h = tn & 7;

  f32x4 acc[4][4];
#pragma unroll
  for (int i = 0; i < 4; ++i)
#pragma unroll
    for (int j = 0; j < 4; ++j) acc[i][j] = zero4();

#define QKV_STAGE(buf, kb)                                                \
  {                                                                       \
    _Pragma("unroll")                                                     \
    for (int c = 0; c < 4; ++c) {                                         \
      const int p = ((c * 4 + w) << 10) + (ln << 4);                      \
      const int g = p >> 11;                                              \
      const int r = (p & 2047) >> 4;                                      \
      gload_lds16(A + ((long)tm * 128 + r) * 1024 + (kb) + g * 8,         \
                  (char*)&lsh[buf][0][0][0][0] + p);                      \
      gload_lds16(Bt + ((long)tn * 128 + r) * 1024 + (kb) + g * 8,        \
                  (char*)&lsh[buf][1][0][0][0] + p);                      \
    }                                                                     \
  }

  QKV_STAGE(0, 0);
  __syncthreads();

  int cur = 0;
  if (which == 2) {
    for (int kb = 0; kb < 1024; kb += 64) {
      const int nb2 = cur ^ 1;
      if (kb + 64 < 1024) QKV_STAGE(nb2, kb + 64);
#pragma unroll
      for (int kk = 0; kk < 2; ++kk) {
        short8 afr[4], bfr[4];
#pragma unroll
        for (int i = 0; i < 4; ++i)
          afr[i] = *(const short8*)&lsh[cur][0][kk * 4 + q4][wm + i * 16 + m15][0];
#pragma unroll
        for (int j = 0; j < 4; ++j)
          bfr[j] = *(const short8*)&lsh[cur][1][kk * 4 + q4][wn + j * 16 + m15][0];
#pragma unroll
        for (int i = 0; i < 4; ++i)
#pragma unroll
          for (int j = 0; j < 4; ++j)
            acc[i][j] = __builtin_amdgcn_mfma_f32_16x16x32_bf16(
                afr[i], bfr[j], acc[i][j], 0, 0, 0);
      }
      __syncthreads();
      cur = nb2;
    }
    // epilogue: acc value at Vt-row dloc = wn+j*16+m15, col mloc =
    // wm+i*16+q4*4+r. Stage sC[dloc][mloc] (XOR-swz), store row-contiguous.
    {
      unsigned short (*sC)[136] = (unsigned short (*)[136])&lsh[0][0][0][0][0];
      const int b = tm >> 5;
      const long bh = b * 8 + h;
#pragma unroll
      for (int j = 0; j < 4; ++j) {
        const int dloc = wn + j * 16 + m15;
        const int sw8 = (dloc & 7) << 3;
#pragma unroll
        for (int i = 0; i < 4; ++i) {
          const int col = (wm + i * 16 + (q4 << 2)) ^ sw8;
          uint2 u;
          u.x = pkbf2(acc[i][j][0], acc[i][j][1]);
          u.y = pkbf2(acc[i][j][2], acc[i][j][3]);
          *(uint2*)&sC[dloc][col] = u;
        }
      }
      __syncthreads();
      const int srow = tid >> 4, sch = tid & 15;
      const int rb = (tm & 31) << 7;
#pragma unroll
      for (int ps = 0; ps < 8; ++ps) {
        const int row = ps * 16 + srow;
        const short8 v = *(const short8*)&sC[row][(sch ^ (row & 7)) << 3];
        *(short8*)&Vt[(bh * 128 + row) * 4096 + rb + (sch << 3)] = v;
      }
    }
  } else {
    for (int kb = 0; kb < 1024; kb += 64) {
      const int nb2 = cur ^ 1;
      if (kb + 64 < 1024) QKV_STAGE(nb2, kb + 64);
#pragma unroll
      for (int kk = 0; kk < 2; ++kk) {
        short8 afr[4], bfr[4];
#pragma unroll
        for (int i = 0; i < 4; ++i)
          afr[i] = *(const short8*)&lsh[cur][0][kk * 4 + q4][wm + i * 16 + m15][0];
#pragma unroll
        for (int j = 0; j < 4; ++j)
          bfr[j] = *(const short8*)&lsh[cur][1][kk * 4 + q4][wn + j * 16 + m15][0];
#pragma unroll
        for (int i = 0; i < 4; ++i)
#pragma unroll
          for (int j = 0; j < 4; ++j)
            acc[i][j] = __builtin_amdgcn_mfma_f32_16x16x32_bf16(
                bfr[j], afr[i], acc[i][j], 0, 0, 0);
      }
      __syncthreads();
      cur = nb2;
    }
    // epilogue: acc value at row mloc = wm+i*16+m15, col dloc =
    // wn+j*16+q4*4+r. Stage sC[mloc][dloc] (XOR-swz), store row-contiguous.
    {
      unsigned short* Dst = (which == 0) ? Qs : Ks;
      const float sc = (which == 0) ? SCALE_Q : 1.0f;
      unsigned short (*sC)[136] = (unsigned short (*)[136])&lsh[0][0][0][0][0];
      const int b = tm >> 5;
      const long bh = b * 8 + h;
#pragma unroll
      for (int i = 0; i < 4; ++i) {
        const int mloc = wm + i * 16 + m15;
        const int sw8 = (mloc & 7) << 3;
#pragma unroll
        for (int j = 0; j < 4; ++j) {
          const int col = (wn + j * 16 + (q4 << 2)) ^ sw8;
          uint2 u;
          u.x = pkbf2(acc[i][j][0] * sc, acc[i][j][1] * sc);
          u.y = pkbf2(acc[i][j][2] * sc, acc[i][j][3] * sc);
          *(uint2*)&sC[mloc][col] = u;
        }
      }
      __syncthreads();
      const int srow = tid >> 4, sch = tid & 15;
      const int rb = (tm & 31) << 7;
#pragma unroll
      for (int ps = 0; ps < 8; ++ps) {
        const int row = ps * 16 + srow;
        const short8 v = *(const short8*)&sC[row][(sch ^ (row & 7)) << 3];
        *(short8*)&Dst[(bh * 4096 + rb + row) * 128 + (sch << 3)] = v;
      }
    }
  }
#undef QKV_STAGE
}

// ---------------- flash attention (unchanged from round 14) ----------------
__global__ __launch_bounds__(256, 2) void k_flash(
    const unsigned short* __restrict__ Qs, const unsigned short* __restrict__ Ks,
    const unsigned short* __restrict__ Vt,
    const unsigned long long* __restrict__ mbits,
    unsigned short* __restrict__ Ob) {
  __shared__ __align__(16) unsigned short lK[2][16][64][8];   // 2 x 16 KB
  __shared__ __align__(16) unsigned short lV[2][8][128][8];   // 2 x 16 KB

  const int tid = threadIdx.x;
  const int w = tid >> 6, ln = tid & 63;
  const int l31 = ln & 31, hi = ln >> 5, hi4 = hi << 2;
  const bool hib = hi != 0;
  (void)hib;
  const int id = blockIdx.x;
  const int xcd = id & 7, jj = id >> 3;           // 64 blocks per XCD
  const int bh = (xcd << 1) | (jj >> 5);          // 2 bh per XCD (4MB K/V in L2)
  const int rowblk = jj & 31;
  const int rbase = rowblk * 128 + w * 32;
  const int qrow = rbase + l31;

  const unsigned short* Qbh = Qs + (long)bh * 524288;
  const unsigned short* Kbh = Ks + (long)bh * 524288;
  const unsigned short* Vbh = Vt + (long)bh * 524288;

  short8 qf[8];
#pragma unroll
  for (int ks = 0; ks < 8; ++ks)
    qf[ks] = *(const short8*)(Qbh + (long)qrow * 128 + ks * 16 + hi * 8);

  f32x16 o[4];
#pragma unroll
  for (int d = 0; d < 4; ++d)
#pragma unroll
    for (int r = 0; r < 16; ++r) o[d][r] = 0.f;
  float lacc = 0.f;

  const bool maskblk = rowblk < 16;   // rows 0..2047

#define STAGE_KV(dst, kvoff)                                              \
  {                                                                       \
    _Pragma("unroll")                                                     \
    for (int c = 0; c < 4; ++c) {                                         \
      const int p = ((c * 4 + w) << 10) + (ln << 4);                      \
      const int cs = p >> 10;                                             \
      const int j = (p & 1023) >> 4;                                      \
      gload_lds16(Kbh + (long)((kvoff) + j) * 128 + cs * 8,               \
                  (char*)&lK[dst][0][0][0] + p);                          \
    }                                                                     \
    _Pragma("unroll")                                                     \
    for (int c = 0; c < 4; ++c) {                                         \
      const int p = ((c * 4 + w) << 10) + (ln << 4);                      \
      const int cv = p >> 11;                                             \
      const int dv = (p & 2047) >> 4;                                     \
      gload_lds16(Vbh + (long)dv * 4096 + (kvoff) + cv * 8,               \
                  (char*)&lV[dst][0][0][0] + p);                          \
    }                                                                     \
  }

#if __has_builtin(__builtin_amdgcn_permlane32_swap)
#define PLSWAP(a, b)                                                      \
  {                                                                       \
    uint2v r_ = __builtin_amdgcn_permlane32_swap((a), (b), false, false); \
    (a) = r_[0]; (b) = r_[1];                                             \
  }
#else
#define PLSWAP(a, b)                                                      \
  {                                                                       \
    const unsigned pa_ = (unsigned)__shfl_xor((int)(a), 32);              \
    const unsigned pb_ = (unsigned)__shfl_xor((int)(b), 32);              \
    const unsigned na_ = hib ? pb_ : (a);                                 \
    const unsigned nb_ = hib ? (b) : pa_;                                 \
    (a) = na_; (b) = nb_;                                                 \
  }
#endif

  STAGE_KV(0, 0);
  __syncthreads();

  int cur = 0;
  for (int kv = 0; kv < 4096; kv += 64) {
    unsigned long long mw = 0ull;
    const bool domask = maskblk && (kv < 2048);
    if (domask) mw = mbits[(long)qrow * 32 + (kv >> 6)];

    const int nb = cur ^ 1;
    if (kv + 64 < 4096) STAGE_KV(nb, kv + 64);

    f32x16 s0, s1;
#pragma unroll
    for (int r = 0; r < 16; ++r) { s0[r] = 0.f; s1[r] = 0.f; }
    __builtin_amdgcn_s_setprio(1);
#pragma unroll
    for (int ks = 0; ks < 8; ++ks) {
      const short8 kf0 = *(const short8*)&lK[cur][ks * 2 + hi][l31][0];
      const short8 kf1 = *(const short8*)&lK[cur][ks * 2 + hi][32 + l31][0];
      s0 = __builtin_amdgcn_mfma_f32_32x32x16_bf16(kf0, qf[ks], s0, 0, 0, 0);
      s1 = __builtin_amdgcn_mfma_f32_32x32x16_bf16(kf1, qf[ks], s1, 0, 0, 0);
    }
    __builtin_amdgcn_s_setprio(0);

    const unsigned mlo = ((unsigned)mw) >> hi4;
    const unsigned mhi = ((unsigned)(mw >> 32)) >> hi4;

    if (domask) {
#pragma unroll
      for (int r = 0; r < 16; ++r) {
        const int c = ((r >> 2) << 3) + (r & 3);
        if (!((mlo >> c) & 1u)) s0[r] = -1e30f;
      }
    }
    float p0[16];
#pragma unroll
    for (int r = 0; r < 16; ++r) {
      p0[r] = __builtin_amdgcn_exp2f(s0[r]);
      lacc += p0[r];
    }
    unsigned w00 = pkbf2(p0[0], p0[1]),   w01 = pkbf2(p0[2], p0[3]);
    unsigned w10 = pkbf2(p0[4], p0[5]),   w11 = pkbf2(p0[6], p0[7]);
    PLSWAP(w00, w10); PLSWAP(w01, w11);
    unsigned w20 = pkbf2(p0[8], p0[9]),   w21 = pkbf2(p0[10], p0[11]);
    unsigned w30 = pkbf2(p0[12], p0[13]), w31 = pkbf2(p0[14], p0[15]);
    PLSWAP(w20, w30); PLSWAP(w21, w31);
    union { unsigned u[4]; short8 s; } pa0, pa1;
    pa0.u[0] = w00; pa0.u[1] = w01; pa0.u[2] = w10; pa0.u[3] = w11;
    pa1.u[0] = w20; pa1.u[1] = w21; pa1.u[2] = w30; pa1.u[3] = w31;

    __builtin_amdgcn_s_setprio(1);
#pragma unroll
    for (int db = 0; db < 4; ++db) {
      const short8 vf0 = *(const short8*)&lV[cur][hi][db * 32 + l31][0];
      o[db] = __builtin_amdgcn_mfma_f32_32x32x16_bf16(pa0.s, vf0, o[db], 0, 0, 0);
      const short8 vf1 = *(const short8*)&lV[cur][2 + hi][db * 32 + l31][0];
      o[db] = __builtin_amdgcn_mfma_f32_32x32x16_bf16(pa1.s, vf1, o[db], 0, 0, 0);
    }
    __builtin_amdgcn_s_setprio(0);

    if (domask) {
#pragma unroll
      for (int r = 0; r < 16; ++r) {
        const int c = ((r >> 2) << 3) + (r & 3);
        if (!((mhi >> c) & 1u)) s1[r] = -1e30f;
      }
    }
    float p1[16];
#pragma unroll
    for (int r = 0; r < 16; ++r) {
      p1[r] = __builtin_amdgcn_exp2f(s1[r]);
      lacc += p1[r];
    }
    unsigned x00 = pkbf2(p1[0], p1[1]),   x01 = pkbf2(p1[2], p1[3]);
    unsigned x10 = pkbf2(p1[4], p1[5]),   x11 = pkbf2(p1[6], p1[7]);
    PLSWAP(x00, x10); PLSWAP(x01, x11);
    unsigned x20 = pkbf2(p1[8], p1[9]),   x21 = pkbf2(p1[10], p1[11]);
    unsigned x30 = pkbf2(p1[12], p1[13]), x31 = pkbf2(p1[14], p1[15]);
    PLSWAP(x20, x30); PLSWAP(x21, x31);
    union { unsigned u[4]; short8 s; } pa2, pa3;
    pa2.u[0] = x00; pa2.u[1] = x01; pa2.u[2] = x10; pa2.u[3] = x11;
    pa3.u[0] = x20; pa3.u[1] = x21; pa3.u[2] = x30; pa3.u[3] = x31;

    __builtin_amdgcn_s_setprio(1);
#pragma unroll
    for (int db = 0; db < 4; ++db) {
      const short8 vf2 = *(const short8*)&lV[cur][4 + hi][db * 32 + l31][0];
      o[db] = __builtin_amdgcn_mfma_f32_32x32x16_bf16(pa2.s, vf2, o[db], 0, 0, 0);
      const short8 vf3 = *(const short8*)&lV[cur][6 + hi][db * 32 + l31][0];
      o[db] = __builtin_amdgcn_mfma_f32_32x32x16_bf16(pa3.s, vf3, o[db], 0, 0, 0);
    }
    __builtin_amdgcn_s_setprio(0);

    __syncthreads();
    cur = nb;
  }
#undef STAGE_KV
#undef PLSWAP

  const float lh = lacc + __shfl_xor(lacc, 32);
  const float linv = 1.0f / lh;

  const int b = bh >> 3, h = bh & 7;
#pragma unroll
  for (int r = 0; r < 16; ++r) {
    const int qr = (r & 3) + ((r >> 2) << 3) + hi4;
    const float li = __shfl(linv, qr);
    const int row = rbase + qr;
    unsigned short* op = Ob + ((long)(b * 4096 + row)) * 1024 + h * 128 + l31;
#pragma unroll
    for (int db = 0; db < 4; ++db)
      op[db * 32] = f2bf(o[db][r] * li);
  }
}

// ---------------- out projection (BK=64, dbuf, coalesced epilogue) ---------
__global__ __launch_bounds__(256, 2) void k_proj_gemm(
    const unsigned short* __restrict__ A,   // [8192][1024]
    const unsigned short* __restrict__ Bt,  // [1024][1024]
    const float* __restrict__ bias, float* __restrict__ Out) {
  __shared__ __align__(16) unsigned short lsh[2][2][8][128][8];  // 64 KB
  const int tid = threadIdx.x;
  const int w = tid >> 6, ln = tid & 63;
  const int m15 = ln & 15, q4 = ln >> 4;
  const int wm = (w >> 1) << 6, wn = (w & 1) << 6;
  const int id = blockIdx.x;
  const int swz = (id & 7) * 64 + (id >> 3);
  const int tn = swz & 7, tm = swz >> 3;

  f32x4 acc[4][4];
#pragma unroll
  for (int i = 0; i < 4; ++i)
#pragma unroll
    for (int j = 0; j < 4; ++j) acc[i][j] = zero4();

#define PROJ_STAGE(buf, kb)                                               \
  {                                                                       \
    _Pragma("unroll")                                                     \
    for (int c = 0; c < 4; ++c) {                                         \
      const int p = ((c * 4 + w) << 10) + (ln << 4);                      \
      const int g = p >> 11;                                              \
      const int r = (p & 2047) >> 4;                                      \
      gload_lds16(A + ((long)tm * 128 + r) * 1024 + (kb) + g * 8,         \
                  (char*)&lsh[buf][0][0][0][0] + p);                      \
      gload_lds16(Bt + ((long)tn * 128 + r) * 1024 + (kb) + g * 8,        \
                  (char*)&lsh[buf][1][0][0][0] + p);                      \
    }                                                                     \
  }

  PROJ_STAGE(0, 0);
  __syncthreads();

  int cur = 0;
  for (int kb = 0; kb < 1024; kb += 64) {
    const int nb2 = cur ^ 1;
    if (kb + 64 < 1024) PROJ_STAGE(nb2, kb + 64);
#pragma unroll
    for (int kk = 0; kk < 2; ++kk) {
      short8 afr[4], bfr[4];
#pragma unroll
      for (int i = 0; i < 4; ++i)
        afr[i] = *(const short8*)&lsh[cur][0][kk * 4 + q4][wm + i * 16 + m15][0];
#pragma unroll
      for (int j = 0; j < 4; ++j)
        bfr[j] = *(const short8*)&lsh[cur][1][kk * 4 + q4][wn + j * 16 + m15][0];
#pragma unroll
      for (int i = 0; i < 4; ++i)
#pragma unroll
        for (int j = 0; j < 4; ++j)
          acc[i][j] = __builtin_amdgcn_mfma_f32_16x16x32_bf16(
              afr[i], bfr[j], acc[i][j], 0, 0, 0);
    }
    __syncthreads();
    cur = nb2;
  }
#undef PROJ_STAGE

  // epilogue: acc value at mloc = wm+i*16+q4*4+r, nloc = wn+j*16+m15.
  // Stage f32 [128][128] (64KB, XOR-swz), read back row-contiguous + bias.
  {
    float (*sF)[128] = (float (*)[128])&lsh[0][0][0][0][0];
#pragma unroll
    for (int i = 0; i < 4; ++i)
#pragma unroll
      for (int r = 0; r < 4; ++r) {
        const int mloc = wm + i * 16 + (q4 << 2) + r;
        const int sw = (mloc & 7) << 2;
#pragma unroll
        for (int j = 0; j < 4; ++j) {
          const int nloc = (wn + j * 16 + m15) ^ sw;
          sF[mloc][nloc] = acc[i][j][r];
        }
      }
    __syncthreads();
    const int prow = tid >> 5, pch = tid & 31;
    const float4 bv = ((const float4*)bias)[(tn << 5) + pch];
#pragma unroll
    for (int ps = 0; ps < 16; ++ps) {
      const int row = (ps << 3) + prow;
      float4 v = *(const float4*)&sF[row][(pch ^ (row & 7)) << 2];
      v.x += bv.x; v.y += bv.y; v.z += bv.z; v.w += bv.w;
      *(float4*)&Out[((long)((tm << 7) + row)) * 1024 + (tn << 7) + (pch << 2)] = v;
    }
  }
}

extern "C" void kernel_launch(void* const* d_in, const int* in_sizes, int n_in,
                              void* d_out, int out_size, void* d_ws,
                              size_t ws_size, hipStream_t stream) {
  const float* x = (const float*)d_in[0];
  const float* Wqkv = (const float*)d_in[1];
  const float* Wout = (const float*)d_in[2];
  const float* bout = (const float*)d_in[3];
  const int* mask = (const int*)d_in[4];
  float* out = (float*)d_out;

  char* ws = (char*)d_ws;
  unsigned short* xb     = (unsigned short*)(ws);            // later Ob
  unsigned short* wqkv_t = (unsigned short*)(ws + 16777216);
  unsigned short* wout_t = (unsigned short*)(ws + 23068672);
  unsigned short* Qs     = (unsigned short*)(ws + 25165824);
  unsigned short* Ks     = (unsigned short*)(ws + 41943040);
  unsigned short* Vt     = (unsigned short*)(ws + 58720256);
  unsigned short* Ob     = xb;                         // xb dead after qkv
  unsigned long long* mbits = (unsigned long long*)wqkv_t;  // wqkv_t dead after qkv

  hipLaunchKernelGGL(k_prep, dim3(12288), dim3(256), 0, stream,
                     x, xb, Wqkv, wqkv_t, Wout, wout_t);
  hipLaunchKernelGGL(k_qkv_gemm, dim3(1536), dim3(256), 0, stream,
                     xb, wqkv_t, Qs, Ks, Vt);
  hipLaunchKernelGGL(k_mask_bits, dim3(16384), dim3(256), 0, stream,
                     mask, mbits);
  hipLaunchKernelGGL(k_flash, dim3(512), dim3(256), 0, stream,
                     Qs, Ks, Vt, mbits, Ob);
  hipLaunchKernelGGL(k_proj_gemm, dim3(512), dim3(256), 0, stream,
                     Ob, wout_t, bout, out);
}

// Round 10
// 411.416 us; speedup vs baseline: 1.0482x; 1.0162x over previous
//
#include <hip/hip_runtime.h>
#include <hip/hip_bf16.h>
#include <stdint.h>

// Round 16: GEMM occupancy restoration. Rounds 12/13 grew GEMM LDS to 64KB
// (BK=64 + dbuf) -> 2 blocks/CU, LDS-capped. m114/m132: the m97-class ~900TF
// depends on 3+ blocks/CU of implicit wave overlap; 64KB kills it (m132:
// BK=128 -> 508 TF for the same reason). Fix: BK=32 + dbuf = 32KB pool ->
// 4-5 blocks/CU. Epilogue staging ALIASES the same 32KB pool (safe after
// the K-loop's final barrier): qkv sC[128][128]bf16 = 32KB; proj two-pass
// [64][128]f32. __launch_bounds__(256,3) caps VGPR at 170 (no spill).
// Flash/prep/mask untouched (attribution).
// Carried: coalesced XOR-swz epilogues (r15), 2-phase dbuf, k_prep fusion,
// mask_bits AFTER qkv (mbits aliases wqkv_t!), 32x32 flash + permlane P,
// XCD-pinned grids (flash FETCH 26.7MB).
//
// ws layout:
//   xb      [8192][1024] bf16  @ 0         (dead after qkv -> Ob)
//   wqkv_t  [3072][1024] bf16  @ 16777216  (dead after qkv -> mbits)
//   wout_t  [1024][1024] bf16  @ 23068672
//   Qs      [16][4096][128]    @ 25165824
//   Ks      [16][4096][128]    @ 41943040
//   Vt      [16][128][4096]    @ 58720256

typedef __attribute__((ext_vector_type(8))) short short8;
typedef __attribute__((ext_vector_type(4))) float f32x4;
typedef __attribute__((ext_vector_type(16))) float f32x16;
typedef unsigned int uint2v __attribute__((ext_vector_type(2)));

// DIM^-0.5 * log2(e): S computed in log2 domain, exp via exp2.
#define SCALE_Q 0.0450842200f

__device__ __forceinline__ unsigned short f2bf(float f) {
  union { float f; unsigned int u; } v;
  v.f = f;
  return (unsigned short)((v.u + 0x7fffu + ((v.u >> 16) & 1u)) >> 16);
}

__device__ __forceinline__ unsigned int pkbf2(float a, float b) {
  __hip_bfloat162 h = __float22bfloat162_rn(make_float2(a, b));
  union { __hip_bfloat162 h; unsigned int u; } c;
  c.h = h;
  return c.u;
}

__device__ __forceinline__ void gload_lds16(const void* g, void* l) {
  __builtin_amdgcn_global_load_lds(
      (const __attribute__((address_space(1))) uint32_t*)(uintptr_t)g,
      (__attribute__((address_space(3))) uint32_t*)(uintptr_t)l, 16, 0, 0);
}

__device__ __forceinline__ f32x4 zero4() {
  f32x4 z; z.x = 0.f; z.y = 0.f; z.z = 0.f; z.w = 0.f; return z;
}

// ---------------- fused prep: cvt_x | cvt_wt(Wqkv) | cvt_wt(Wout) ----------
__global__ __launch_bounds__(256) void k_prep(
    const float* __restrict__ x, unsigned short* __restrict__ xb,
    const float* __restrict__ Wqkv, unsigned short* __restrict__ wqkv_t,
    const float* __restrict__ Wout, unsigned short* __restrict__ wout_t) {
  __shared__ float t[32][33];
  const int id = blockIdx.x;
  const int tid = threadIdx.x;
  if (id < 8192) {
    const int i = id * 256 + tid;
    const float4 v = ((const float4*)x)[i];
    ushort4 o;
    o.x = f2bf(v.x); o.y = f2bf(v.y); o.z = f2bf(v.z); o.w = f2bf(v.w);
    ((ushort4*)xb)[i] = o;
  } else {
    const float* w;
    unsigned short* wt;
    int Nn, bx, by;
    if (id < 11264) {
      const int r = id - 8192;            // 3072 blocks (96 x 32)
      w = Wqkv; wt = wqkv_t; Nn = 3072; bx = r % 96; by = r / 96;
    } else {
      const int r = id - 11264;           // 1024 blocks (32 x 32)
      w = Wout; wt = wout_t; Nn = 1024; bx = r % 32; by = r / 32;
    }
    const int n0 = bx << 5, k0 = by << 5;
    const int c = tid & 31, r8 = tid >> 5;
#pragma unroll
    for (int i = 0; i < 4; ++i) {
      const int r = (i << 3) + r8;
      t[r][c] = w[(long)(k0 + r) * Nn + n0 + c];
    }
    __syncthreads();
#pragma unroll
    for (int i = 0; i < 4; ++i) {
      const int r = (i << 3) + r8;
      wt[(long)(n0 + r) * 1024 + k0 + c] = f2bf(t[c][r]);
    }
  }
}

// ---------------- mask -> bitmask (AFTER qkv_gemm: mbits aliases wqkv_t) ----
__global__ __launch_bounds__(256) void k_mask_bits(
    const int* __restrict__ m, unsigned long long* __restrict__ mb) {
  const int t = blockIdx.x * 256 + threadIdx.x;
  const unsigned long long b = __ballot(m[t] != 0);
  if ((threadIdx.x & 63) == 0) mb[t >> 6] = b;
}

// ---------------- QKV GEMM (BK=32, 2-phase dbuf, 32KB pool) ----------------
// smem pool: staging lA[2]@0 (8KB each), lB[2]@16384; epilogue sC aliases
// the whole 32KB after the K-loop's final barrier.
__global__ __launch_bounds__(256, 3) void k_qkv_gemm(
    const unsigned short* __restrict__ A,   // [8192][1024]
    const unsigned short* __restrict__ Bt,  // [3072][1024]
    unsigned short* __restrict__ Qs, unsigned short* __restrict__ Ks,
    unsigned short* __restrict__ Vt) {
  __shared__ __align__(16) char smem[32768];
  typedef unsigned short stageT[4][128][8];   // 8KB: [kq4][row][8elem]
  stageT* lA = (stageT*)smem;                 // lA[buf]
  stageT* lB = (stageT*)(smem + 16384);       // lB[buf]
  const int tid = threadIdx.x;
  const int w = tid >> 6, ln = tid & 63;
  const int m15 = ln & 15, q4 = ln >> 4;
  const int wm = (w >> 1) << 6, wn = (w & 1) << 6;
  const int id = blockIdx.x;
  const int swz = (id & 7) * 192 + (id >> 3);   // XCD-chunked remap
  const int tn = swz % 24, tm = swz / 24;
  const int which = tn >> 3;   // 0=Q 1=K 2=V (uniform per block)
  const int h = tn & 7;

  f32x4 acc[4][4];
#pragma unroll
  for (int i = 0; i < 4; ++i)
#pragma unroll
    for (int j = 0; j < 4; ++j) acc[i][j] = zero4();

#define QKV_STAGE(buf, kb)                                                \
  {                                                                       \
    _Pragma("unroll")                                                     \
    for (int c = 0; c < 2; ++c) {                                         \
      const int p = ((c * 4 + w) << 10) + (ln << 4);                      \
      const int g = p >> 11;                                              \
      const int r = (p & 2047) >> 4;                                      \
      gload_lds16(A + ((long)tm * 128 + r) * 1024 + (kb) + g * 8,         \
                  smem + (buf) * 8192 + p);                               \
      gload_lds16(Bt + ((long)tn * 128 + r) * 1024 + (kb) + g * 8,        \
                  smem + 16384 + (buf) * 8192 + p);                       \
    }                                                                     \
  }

  QKV_STAGE(0, 0);
  __syncthreads();

  int cur = 0;
  if (which == 2) {
    for (int kb = 0; kb < 1024; kb += 32) {
      const int nb2 = cur ^ 1;
      if (kb + 32 < 1024) QKV_STAGE(nb2, kb + 32);
      short8 afr[4], bfr[4];
#pragma unroll
      for (int i = 0; i < 4; ++i)
        afr[i] = *(const short8*)&lA[cur][q4][wm + i * 16 + m15][0];
#pragma unroll
      for (int j = 0; j < 4; ++j)
        bfr[j] = *(const short8*)&lB[cur][q4][wn + j * 16 + m15][0];
#pragma unroll
      for (int i = 0; i < 4; ++i)
#pragma unroll
        for (int j = 0; j < 4; ++j)
          acc[i][j] = __builtin_amdgcn_mfma_f32_16x16x32_bf16(
              afr[i], bfr[j], acc[i][j], 0, 0, 0);
      __syncthreads();
      cur = nb2;
    }
    // epilogue (aliases pool): sC[dloc=Vt-row d][mloc col], XOR-swz, then
    // row-contiguous 16B stores.
    {
      unsigned short (*sC)[128] = (unsigned short (*)[128])smem;
      const int b = tm >> 5;
      const long bh = b * 8 + h;
#pragma unroll
      for (int j = 0; j < 4; ++j) {
        const int dloc = wn + j * 16 + m15;
        const int sw8 = (dloc & 7) << 3;
#pragma unroll
        for (int i = 0; i < 4; ++i) {
          const int col = (wm + i * 16 + (q4 << 2)) ^ sw8;
          uint2 u;
          u.x = pkbf2(acc[i][j][0], acc[i][j][1]);
          u.y = pkbf2(acc[i][j][2], acc[i][j][3]);
          *(uint2*)&sC[dloc][col] = u;
        }
      }
      __syncthreads();
      const int srow = tid >> 4, sch = tid & 15;
      const int rb = (tm & 31) << 7;
#pragma unroll
      for (int ps = 0; ps < 8; ++ps) {
        const int row = ps * 16 + srow;
        const short8 v = *(const short8*)&sC[row][(sch ^ (row & 7)) << 3];
        *(short8*)&Vt[(bh * 128 + row) * 4096 + rb + (sch << 3)] = v;
      }
    }
  } else {
    for (int kb = 0; kb < 1024; kb += 32) {
      const int nb2 = cur ^ 1;
      if (kb + 32 < 1024) QKV_STAGE(nb2, kb + 32);
      short8 afr[4], bfr[4];
#pragma unroll
      for (int i = 0; i < 4; ++i)
        afr[i] = *(const short8*)&lA[cur][q4][wm + i * 16 + m15][0];
#pragma unroll
      for (int j = 0; j < 4; ++j)
        bfr[j] = *(const short8*)&lB[cur][q4][wn + j * 16 + m15][0];
#pragma unroll
      for (int i = 0; i < 4; ++i)
#pragma unroll
        for (int j = 0; j < 4; ++j)
          acc[i][j] = __builtin_amdgcn_mfma_f32_16x16x32_bf16(
              bfr[j], afr[i], acc[i][j], 0, 0, 0);
      __syncthreads();
      cur = nb2;
    }
    // epilogue: sC[mloc row][dloc col], XOR-swz, row-contiguous stores.
    {
      unsigned short* Dst = (which == 0) ? Qs : Ks;
      const float sc = (which == 0) ? SCALE_Q : 1.0f;
      unsigned short (*sC)[128] = (unsigned short (*)[128])smem;
      const int b = tm >> 5;
      const long bh = b * 8 + h;
#pragma unroll
      for (int i = 0; i < 4; ++i) {
        const int mloc = wm + i * 16 + m15;
        const int sw8 = (mloc & 7) << 3;
#pragma unroll
        for (int j = 0; j < 4; ++j) {
          const int col = (wn + j * 16 + (q4 << 2)) ^ sw8;
          uint2 u;
          u.x = pkbf2(acc[i][j][0] * sc, acc[i][j][1] * sc);
          u.y = pkbf2(acc[i][j][2] * sc, acc[i][j][3] * sc);
          *(uint2*)&sC[mloc][col] = u;
        }
      }
      __syncthreads();
      const int srow = tid >> 4, sch = tid & 15;
      const int rb = (tm & 31) << 7;
#pragma unroll
      for (int ps = 0; ps < 8; ++ps) {
        const int row = ps * 16 + srow;
        const short8 v = *(const short8*)&sC[row][(sch ^ (row & 7)) << 3];
        *(short8*)&Dst[(bh * 4096 + rb + row) * 128 + (sch << 3)] = v;
      }
    }
  }
#undef QKV_STAGE
}

// ---------------- flash attention (unchanged from round 14/15) -------------
__global__ __launch_bounds__(256, 2) void k_flash(
    const unsigned short* __restrict__ Qs, const unsigned short* __restrict__ Ks,
    const unsigned short* __restrict__ Vt,
    const unsigned long long* __restrict__ mbits,
    unsigned short* __restrict__ Ob) {
  __shared__ __align__(16) unsigned short lK[2][16][64][8];   // 2 x 16 KB
  __shared__ __align__(16) unsigned short lV[2][8][128][8];   // 2 x 16 KB

  const int tid = threadIdx.x;
  const int w = tid >> 6, ln = tid & 63;
  const int l31 = ln & 31, hi = ln >> 5, hi4 = hi << 2;
  const bool hib = hi != 0;
  (void)hib;
  const int id = blockIdx.x;
  const int xcd = id & 7, jj = id >> 3;           // 64 blocks per XCD
  const int bh = (xcd << 1) | (jj >> 5);          // 2 bh per XCD (4MB K/V in L2)
  const int rowblk = jj & 31;
  const int rbase = rowblk * 128 + w * 32;
  const int qrow = rbase + l31;

  const unsigned short* Qbh = Qs + (long)bh * 524288;
  const unsigned short* Kbh = Ks + (long)bh * 524288;
  const unsigned short* Vbh = Vt + (long)bh * 524288;

  short8 qf[8];
#pragma unroll
  for (int ks = 0; ks < 8; ++ks)
    qf[ks] = *(const short8*)(Qbh + (long)qrow * 128 + ks * 16 + hi * 8);

  f32x16 o[4];
#pragma unroll
  for (int d = 0; d < 4; ++d)
#pragma unroll
    for (int r = 0; r < 16; ++r) o[d][r] = 0.f;
  float lacc = 0.f;

  const bool maskblk = rowblk < 16;   // rows 0..2047

#define STAGE_KV(dst, kvoff)                                              \
  {                                                                       \
    _Pragma("unroll")                                                     \
    for (int c = 0; c < 4; ++c) {                                         \
      const int p = ((c * 4 + w) << 10) + (ln << 4);                      \
      const int cs = p >> 10;                                             \
      const int j = (p & 1023) >> 4;                                      \
      gload_lds16(Kbh + (long)((kvoff) + j) * 128 + cs * 8,               \
                  (char*)&lK[dst][0][0][0] + p);                          \
    }                                                                     \
    _Pragma("unroll")                                                     \
    for (int c = 0; c < 4; ++c) {                                         \
      const int p = ((c * 4 + w) << 10) + (ln << 4);                      \
      const int cv = p >> 11;                                             \
      const int dv = (p & 2047) >> 4;                                     \
      gload_lds16(Vbh + (long)dv * 4096 + (kvoff) + cv * 8,               \
                  (char*)&lV[dst][0][0][0] + p);                          \
    }                                                                     \
  }

#if __has_builtin(__builtin_amdgcn_permlane32_swap)
#define PLSWAP(a, b)                                                      \
  {                                                                       \
    uint2v r_ = __builtin_amdgcn_permlane32_swap((a), (b), false, false); \
    (a) = r_[0]; (b) = r_[1];                                             \
  }
#else
#define PLSWAP(a, b)                                                      \
  {                                                                       \
    const unsigned pa_ = (unsigned)__shfl_xor((int)(a), 32);              \
    const unsigned pb_ = (unsigned)__shfl_xor((int)(b), 32);              \
    const unsigned na_ = hib ? pb_ : (a);                                 \
    const unsigned nb_ = hib ? (b) : pa_;                                 \
    (a) = na_; (b) = nb_;                                                 \
  }
#endif

  STAGE_KV(0, 0);
  __syncthreads();

  int cur = 0;
  for (int kv = 0; kv < 4096; kv += 64) {
    unsigned long long mw = 0ull;
    const bool domask = maskblk && (kv < 2048);
    if (domask) mw = mbits[(long)qrow * 32 + (kv >> 6)];

    const int nb = cur ^ 1;
    if (kv + 64 < 4096) STAGE_KV(nb, kv + 64);

    f32x16 s0, s1;
#pragma unroll
    for (int r = 0; r < 16; ++r) { s0[r] = 0.f; s1[r] = 0.f; }
    __builtin_amdgcn_s_setprio(1);
#pragma unroll
    for (int ks = 0; ks < 8; ++ks) {
      const short8 kf0 = *(const short8*)&lK[cur][ks * 2 + hi][l31][0];
      const short8 kf1 = *(const short8*)&lK[cur][ks * 2 + hi][32 + l31][0];
      s0 = __builtin_amdgcn_mfma_f32_32x32x16_bf16(kf0, qf[ks], s0, 0, 0, 0);
      s1 = __builtin_amdgcn_mfma_f32_32x32x16_bf16(kf1, qf[ks], s1, 0, 0, 0);
    }
    __builtin_amdgcn_s_setprio(0);

    const unsigned mlo = ((unsigned)mw) >> hi4;
    const unsigned mhi = ((unsigned)(mw >> 32)) >> hi4;

    if (domask) {
#pragma unroll
      for (int r = 0; r < 16; ++r) {
        const int c = ((r >> 2) << 3) + (r & 3);
        if (!((mlo >> c) & 1u)) s0[r] = -1e30f;
      }
    }
    float p0[16];
#pragma unroll
    for (int r = 0; r < 16; ++r) {
      p0[r] = __builtin_amdgcn_exp2f(s0[r]);
      lacc += p0[r];
    }
    unsigned w00 = pkbf2(p0[0], p0[1]),   w01 = pkbf2(p0[2], p0[3]);
    unsigned w10 = pkbf2(p0[4], p0[5]),   w11 = pkbf2(p0[6], p0[7]);
    PLSWAP(w00, w10); PLSWAP(w01, w11);
    unsigned w20 = pkbf2(p0[8], p0[9]),   w21 = pkbf2(p0[10], p0[11]);
    unsigned w30 = pkbf2(p0[12], p0[13]), w31 = pkbf2(p0[14], p0[15]);
    PLSWAP(w20, w30); PLSWAP(w21, w31);
    union { unsigned u[4]; short8 s; } pa0, pa1;
    pa0.u[0] = w00; pa0.u[1] = w01; pa0.u[2] = w10; pa0.u[3] = w11;
    pa1.u[0] = w20; pa1.u[1] = w21; pa1.u[2] = w30; pa1.u[3] = w31;

    __builtin_amdgcn_s_setprio(1);
#pragma unroll
    for (int db = 0; db < 4; ++db) {
      const short8 vf0 = *(const short8*)&lV[cur][hi][db * 32 + l31][0];
      o[db] = __builtin_amdgcn_mfma_f32_32x32x16_bf16(pa0.s, vf0, o[db], 0, 0, 0);
      const short8 vf1 = *(const short8*)&lV[cur][2 + hi][db * 32 + l31][0];
      o[db] = __builtin_amdgcn_mfma_f32_32x32x16_bf16(pa1.s, vf1, o[db], 0, 0, 0);
    }
    __builtin_amdgcn_s_setprio(0);

    if (domask) {
#pragma unroll
      for (int r = 0; r < 16; ++r) {
        const int c = ((r >> 2) << 3) + (r & 3);
        if (!((mhi >> c) & 1u)) s1[r] = -1e30f;
      }
    }
    float p1[16];
#pragma unroll
    for (int r = 0; r < 16; ++r) {
      p1[r] = __builtin_amdgcn_exp2f(s1[r]);
      lacc += p1[r];
    }
    unsigned x00 = pkbf2(p1[0], p1[1]),   x01 = pkbf2(p1[2], p1[3]);
    unsigned x10 = pkbf2(p1[4], p1[5]),   x11 = pkbf2(p1[6], p1[7]);
    PLSWAP(x00, x10); PLSWAP(x01, x11);
    unsigned x20 = pkbf2(p1[8], p1[9]),   x21 = pkbf2(p1[10], p1[11]);
    unsigned x30 = pkbf2(p1[12], p1[13]), x31 = pkbf2(p1[14], p1[15]);
    PLSWAP(x20, x30); PLSWAP(x21, x31);
    union { unsigned u[4]; short8 s; } pa2, pa3;
    pa2.u[0] = x00; pa2.u[1] = x01; pa2.u[2] = x10; pa2.u[3] = x11;
    pa3.u[0] = x20; pa3.u[1] = x21; pa3.u[2] = x30; pa3.u[3] = x31;

    __builtin_amdgcn_s_setprio(1);
#pragma unroll
    for (int db = 0; db < 4; ++db) {
      const short8 vf2 = *(const short8*)&lV[cur][4 + hi][db * 32 + l31][0];
      o[db] = __builtin_amdgcn_mfma_f32_32x32x16_bf16(pa2.s, vf2, o[db], 0, 0, 0);
      const short8 vf3 = *(const short8*)&lV[cur][6 + hi][db * 32 + l31][0];
      o[db] = __builtin_amdgcn_mfma_f32_32x32x16_bf16(pa3.s, vf3, o[db], 0, 0, 0);
    }
    __builtin_amdgcn_s_setprio(0);

    __syncthreads();
    cur = nb;
  }
#undef STAGE_KV
#undef PLSWAP

  const float lh = lacc + __shfl_xor(lacc, 32);
  const float linv = 1.0f / lh;

  const int b = bh >> 3, h = bh & 7;
#pragma unroll
  for (int r = 0; r < 16; ++r) {
    const int qr = (r & 3) + ((r >> 2) << 3) + hi4;
    const float li = __shfl(linv, qr);
    const int row = rbase + qr;
    unsigned short* op = Ob + ((long)(b * 4096 + row)) * 1024 + h * 128 + l31;
#pragma unroll
    for (int db = 0; db < 4; ++db)
      op[db * 32] = f2bf(o[db][r] * li);
  }
}

// ---------------- out projection (BK=32, dbuf, 32KB pool, 2-pass epi) ------
__global__ __launch_bounds__(256, 3) void k_proj_gemm(
    const unsigned short* __restrict__ A,   // [8192][1024]
    const unsigned short* __restrict__ Bt,  // [1024][1024]
    const float* __restrict__ bias, float* __restrict__ Out) {
  __shared__ __align__(16) char smem[32768];
  typedef unsigned short stageT[4][128][8];
  stageT* lA = (stageT*)smem;
  stageT* lB = (stageT*)(smem + 16384);
  const int tid = threadIdx.x;
  const int w = tid >> 6, ln = tid & 63;
  const int m15 = ln & 15, q4 = ln >> 4;
  const int wm = (w >> 1) << 6, wn = (w & 1) << 6;
  const int id = blockIdx.x;
  const int swz = (id & 7) * 64 + (id >> 3);
  const int tn = swz & 7, tm = swz >> 3;

  f32x4 acc[4][4];
#pragma unroll
  for (int i = 0; i < 4; ++i)
#pragma unroll
    for (int j = 0; j < 4; ++j) acc[i][j] = zero4();

#define PROJ_STAGE(buf, kb)                                               \
  {                                                                       \
    _Pragma("unroll")                                                     \
    for (int c = 0; c < 2; ++c) {                                         \
      const int p = ((c * 4 + w) << 10) + (ln << 4);                      \
      const int g = p >> 11;                                              \
      const int r = (p & 2047) >> 4;                                      \
      gload_lds16(A + ((long)tm * 128 + r) * 1024 + (kb) + g * 8,         \
                  smem + (buf) * 8192 + p);                               \
      gload_lds16(Bt + ((long)tn * 128 + r) * 1024 + (kb) + g * 8,        \
                  smem + 16384 + (buf) * 8192 + p);                       \
    }                                                                     \
  }

  PROJ_STAGE(0, 0);
  __syncthreads();

  int cur = 0;
  for (int kb = 0; kb < 1024; kb += 32) {
    const int nb2 = cur ^ 1;
    if (kb + 32 < 1024) PROJ_STAGE(nb2, kb + 32);
    short8 afr[4], bfr[4];
#pragma unroll
    for (int i = 0; i < 4; ++i)
      afr[i] = *(const short8*)&lA[cur][q4][wm + i * 16 + m15][0];
#pragma unroll
    for (int j = 0; j < 4; ++j)
      bfr[j] = *(const short8*)&lB[cur][q4][wn + j * 16 + m15][0];
#pragma unroll
    for (int i = 0; i < 4; ++i)
#pragma unroll
      for (int j = 0; j < 4; ++j)
        acc[i][j] = __builtin_amdgcn_mfma_f32_16x16x32_bf16(
            afr[i], bfr[j], acc[i][j], 0, 0, 0);
    __syncthreads();
    cur = nb2;
  }
#undef PROJ_STAGE

  // two-pass epilogue in the 32KB pool: pass p stages rows p*64..p*64+63
  // (f32 [64][128], XOR-swz), reads back row-contiguous + bias.
  {
    float (*sF)[128] = (float (*)[128])smem;
    const int prow = tid >> 5, pch = tid & 31;
    const float4 bv = ((const float4*)bias)[(tn << 5) + pch];
#pragma unroll
    for (int pass = 0; pass < 2; ++pass) {
      __syncthreads();
      if ((w >> 1) == pass) {   // waves whose wm == pass*64
#pragma unroll
        for (int i = 0; i < 4; ++i)
#pragma unroll
          for (int r = 0; r < 4; ++r) {
            const int ml = i * 16 + (q4 << 2) + r;      // 0..63
            const int sw = (ml & 7) << 2;
#pragma unroll
            for (int j = 0; j < 4; ++j)
              sF[ml][(wn + j * 16 + m15) ^ sw] = acc[i][j][r];
          }
      }
      __syncthreads();
#pragma unroll
      for (int ps = 0; ps < 8; ++ps) {
        const int rl = (ps << 3) + prow;                // 0..63
        float4 v = *(const float4*)&sF[rl][(pch ^ (rl & 7)) << 2];
        v.x += bv.x; v.y += bv.y; v.z += bv.z; v.w += bv.w;
        const int row = (tm << 7) + (pass << 6) + rl;
        *(float4*)&Out[(long)row * 1024 + (tn << 7) + (pch << 2)] = v;
      }
    }
  }
}

extern "C" void kernel_launch(void* const* d_in, const int* in_sizes, int n_in,
                              void* d_out, int out_size, void* d_ws,
                              size_t ws_size, hipStream_t stream) {
  const float* x = (const float*)d_in[0];
  const float* Wqkv = (const float*)d_in[1];
  const float* Wout = (const float*)d_in[2];
  const float* bout = (const float*)d_in[3];
  const int* mask = (const int*)d_in[4];
  float* out = (float*)d_out;

  char* ws = (char*)d_ws;
  unsigned short* xb     = (unsigned short*)(ws);            // later Ob
  unsigned short* wqkv_t = (unsigned short*)(ws + 16777216);
  unsigned short* wout_t = (unsigned short*)(ws + 23068672);
  unsigned short* Qs     = (unsigned short*)(ws + 25165824);
  unsigned short* Ks     = (unsigned short*)(ws + 41943040);
  unsigned short* Vt     = (unsigned short*)(ws + 58720256);
  unsigned short* Ob     = xb;                         // xb dead after qkv
  unsigned long long* mbits = (unsigned long long*)wqkv_t;  // wqkv_t dead after qkv

  hipLaunchKernelGGL(k_prep, dim3(12288), dim3(256), 0, stream,
                     x, xb, Wqkv, wqkv_t, Wout, wout_t);
  hipLaunchKernelGGL(k_qkv_gemm, dim3(1536), dim3(256), 0, stream,
                     xb, wqkv_t, Qs, Ks, Vt);
  hipLaunchKernelGGL(k_mask_bits, dim3(16384), dim3(256), 0, stream,
                     mask, mbits);
  hipLaunchKernelGGL(k_flash, dim3(512), dim3(256), 0, stream,
                     Qs, Ks, Vt, mbits, Ob);
  hipLaunchKernelGGL(k_proj_gemm, dim3(512), dim3(256), 0, stream,
                     Ob, wout_t, bout, out);
}

// Round 11
// 406.204 us; speedup vs baseline: 1.0617x; 1.0128x over previous
//
#include <hip/hip_runtime.h>
#include <hip/hip_bf16.h>
#include <stdint.h>

// Round 17: GEMM L2 walk-order fix. The qkv XCD swizzle walked tn FASTEST
// within an XCD -> each XCD cycles all 24 B-panels (6MB > 4MB L2) per tm
// row -> B thrashes: ~384MB HBM fetch for 22MB of inputs (~61us of pure
// HBM time). This is why BK/dbuf/occupancy rounds were all ~neutral: qkv
// was HBM-bound the whole time. Fix: tm-fastest walk (tn=j>>3,
// tm=xcd*8+(j&7)) -> 8 same-XCD blocks share one 256KB B-panel; the XCD's
// 8 A-panels (2MB) stay L2-resident. Chip fetch ~64MB (6x less). Same
// remap for proj. NOTHING else changed (flash/prep/mask byte-identical).
// Carried: BK=32+dbuf 32KB pool (r16), coalesced XOR-swz epilogues (r15),
// k_prep fusion, mask_bits AFTER qkv (mbits aliases wqkv_t!), 32x32 flash
// + permlane P, flash XCD-pinning (FETCH 26.7MB).
//
// ws layout:
//   xb      [8192][1024] bf16  @ 0         (dead after qkv -> Ob)
//   wqkv_t  [3072][1024] bf16  @ 16777216  (dead after qkv -> mbits)
//   wout_t  [1024][1024] bf16  @ 23068672
//   Qs      [16][4096][128]    @ 25165824
//   Ks      [16][4096][128]    @ 41943040
//   Vt      [16][128][4096]    @ 58720256

typedef __attribute__((ext_vector_type(8))) short short8;
typedef __attribute__((ext_vector_type(4))) float f32x4;
typedef __attribute__((ext_vector_type(16))) float f32x16;
typedef unsigned int uint2v __attribute__((ext_vector_type(2)));

// DIM^-0.5 * log2(e): S computed in log2 domain, exp via exp2.
#define SCALE_Q 0.0450842200f

__device__ __forceinline__ unsigned short f2bf(float f) {
  union { float f; unsigned int u; } v;
  v.f = f;
  return (unsigned short)((v.u + 0x7fffu + ((v.u >> 16) & 1u)) >> 16);
}

__device__ __forceinline__ unsigned int pkbf2(float a, float b) {
  __hip_bfloat162 h = __float22bfloat162_rn(make_float2(a, b));
  union { __hip_bfloat162 h; unsigned int u; } c;
  c.h = h;
  return c.u;
}

__device__ __forceinline__ void gload_lds16(const void* g, void* l) {
  __builtin_amdgcn_global_load_lds(
      (const __attribute__((address_space(1))) uint32_t*)(uintptr_t)g,
      (__attribute__((address_space(3))) uint32_t*)(uintptr_t)l, 16, 0, 0);
}

__device__ __forceinline__ f32x4 zero4() {
  f32x4 z; z.x = 0.f; z.y = 0.f; z.z = 0.f; z.w = 0.f; return z;
}

// ---------------- fused prep: cvt_x | cvt_wt(Wqkv) | cvt_wt(Wout) ----------
__global__ __launch_bounds__(256) void k_prep(
    const float* __restrict__ x, unsigned short* __restrict__ xb,
    const float* __restrict__ Wqkv, unsigned short* __restrict__ wqkv_t,
    const float* __restrict__ Wout, unsigned short* __restrict__ wout_t) {
  __shared__ float t[32][33];
  const int id = blockIdx.x;
  const int tid = threadIdx.x;
  if (id < 8192) {
    const int i = id * 256 + tid;
    const float4 v = ((const float4*)x)[i];
    ushort4 o;
    o.x = f2bf(v.x); o.y = f2bf(v.y); o.z = f2bf(v.z); o.w = f2bf(v.w);
    ((ushort4*)xb)[i] = o;
  } else {
    const float* w;
    unsigned short* wt;
    int Nn, bx, by;
    if (id < 11264) {
      const int r = id - 8192;            // 3072 blocks (96 x 32)
      w = Wqkv; wt = wqkv_t; Nn = 3072; bx = r % 96; by = r / 96;
    } else {
      const int r = id - 11264;           // 1024 blocks (32 x 32)
      w = Wout; wt = wout_t; Nn = 1024; bx = r % 32; by = r / 32;
    }
    const int n0 = bx << 5, k0 = by << 5;
    const int c = tid & 31, r8 = tid >> 5;
#pragma unroll
    for (int i = 0; i < 4; ++i) {
      const int r = (i << 3) + r8;
      t[r][c] = w[(long)(k0 + r) * Nn + n0 + c];
    }
    __syncthreads();
#pragma unroll
    for (int i = 0; i < 4; ++i) {
      const int r = (i << 3) + r8;
      wt[(long)(n0 + r) * 1024 + k0 + c] = f2bf(t[c][r]);
    }
  }
}

// ---------------- mask -> bitmask (AFTER qkv_gemm: mbits aliases wqkv_t) ----
__global__ __launch_bounds__(256) void k_mask_bits(
    const int* __restrict__ m, unsigned long long* __restrict__ mb) {
  const int t = blockIdx.x * 256 + threadIdx.x;
  const unsigned long long b = __ballot(m[t] != 0);
  if ((threadIdx.x & 63) == 0) mb[t >> 6] = b;
}

// ---------------- QKV GEMM (BK=32, dbuf, tm-fastest XCD walk) --------------
__global__ __launch_bounds__(256, 3) void k_qkv_gemm(
    const unsigned short* __restrict__ A,   // [8192][1024]
    const unsigned short* __restrict__ Bt,  // [3072][1024]
    unsigned short* __restrict__ Qs, unsigned short* __restrict__ Ks,
    unsigned short* __restrict__ Vt) {
  __shared__ __align__(16) char smem[32768];
  typedef unsigned short stageT[4][128][8];   // 8KB: [kq4][row][8elem]
  stageT* lA = (stageT*)smem;                 // lA[buf]
  stageT* lB = (stageT*)(smem + 16384);       // lB[buf]
  const int tid = threadIdx.x;
  const int w = tid >> 6, ln = tid & 63;
  const int m15 = ln & 15, q4 = ln >> 4;
  const int wm = (w >> 1) << 6, wn = (w & 1) << 6;
  const int id = blockIdx.x;
  // tm-fastest within-XCD walk: 8 consecutive same-XCD blocks share one
  // 256KB B-panel; the XCD's 8 A-panels (2MB) stay L2-resident.
  const int xcd = id & 7, j = id >> 3;        // j in [0,192)
  const int tn = j >> 3;                      // 0..23 (slow)
  const int tm = (xcd << 3) + (j & 7);        // 8 tm per XCD (fast)
  const int which = tn >> 3;   // 0=Q 1=K 2=V (uniform per block)
  const int h = tn & 7;

  f32x4 acc[4][4];
#pragma unroll
  for (int i = 0; i < 4; ++i)
#pragma unroll
    for (int j2 = 0; j2 < 4; ++j2) acc[i][j2] = zero4();

#define QKV_STAGE(buf, kb)                                                \
  {                                                                       \
    _Pragma("unroll")                                                     \
    for (int c = 0; c < 2; ++c) {                                         \
      const int p = ((c * 4 + w) << 10) + (ln << 4);                      \
      const int g = p >> 11;                                              \
      const int r = (p & 2047) >> 4;                                      \
      gload_lds16(A + ((long)tm * 128 + r) * 1024 + (kb) + g * 8,         \
                  smem + (buf) * 8192 + p);                               \
      gload_lds16(Bt + ((long)tn * 128 + r) * 1024 + (kb) + g * 8,        \
                  smem + 16384 + (buf) * 8192 + p);                       \
    }                                                                     \
  }

  QKV_STAGE(0, 0);
  __syncthreads();

  int cur = 0;
  if (which == 2) {
    for (int kb = 0; kb < 1024; kb += 32) {
      const int nb2 = cur ^ 1;
      if (kb + 32 < 1024) QKV_STAGE(nb2, kb + 32);
      short8 afr[4], bfr[4];
#pragma unroll
      for (int i = 0; i < 4; ++i)
        afr[i] = *(const short8*)&lA[cur][q4][wm + i * 16 + m15][0];
#pragma unroll
      for (int j2 = 0; j2 < 4; ++j2)
        bfr[j2] = *(const short8*)&lB[cur][q4][wn + j2 * 16 + m15][0];
#pragma unroll
      for (int i = 0; i < 4; ++i)
#pragma unroll
        for (int j2 = 0; j2 < 4; ++j2)
          acc[i][j2] = __builtin_amdgcn_mfma_f32_16x16x32_bf16(
              afr[i], bfr[j2], acc[i][j2], 0, 0, 0);
      __syncthreads();
      cur = nb2;
    }
    // epilogue (aliases pool): sC[dloc][mloc], XOR-swz, coalesced stores.
    {
      unsigned short (*sC)[128] = (unsigned short (*)[128])smem;
      const int b = tm >> 5;
      const long bh = b * 8 + h;
#pragma unroll
      for (int j2 = 0; j2 < 4; ++j2) {
        const int dloc = wn + j2 * 16 + m15;
        const int sw8 = (dloc & 7) << 3;
#pragma unroll
        for (int i = 0; i < 4; ++i) {
          const int col = (wm + i * 16 + (q4 << 2)) ^ sw8;
          uint2 u;
          u.x = pkbf2(acc[i][j2][0], acc[i][j2][1]);
          u.y = pkbf2(acc[i][j2][2], acc[i][j2][3]);
          *(uint2*)&sC[dloc][col] = u;
        }
      }
      __syncthreads();
      const int srow = tid >> 4, sch = tid & 15;
      const int rb = (tm & 31) << 7;
#pragma unroll
      for (int ps = 0; ps < 8; ++ps) {
        const int row = ps * 16 + srow;
        const short8 v = *(const short8*)&sC[row][(sch ^ (row & 7)) << 3];
        *(short8*)&Vt[(bh * 128 + row) * 4096 + rb + (sch << 3)] = v;
      }
    }
  } else {
    for (int kb = 0; kb < 1024; kb += 32) {
      const int nb2 = cur ^ 1;
      if (kb + 32 < 1024) QKV_STAGE(nb2, kb + 32);
      short8 afr[4], bfr[4];
#pragma unroll
      for (int i = 0; i < 4; ++i)
        afr[i] = *(const short8*)&lA[cur][q4][wm + i * 16 + m15][0];
#pragma unroll
      for (int j2 = 0; j2 < 4; ++j2)
        bfr[j2] = *(const short8*)&lB[cur][q4][wn + j2 * 16 + m15][0];
#pragma unroll
      for (int i = 0; i < 4; ++i)
#pragma unroll
        for (int j2 = 0; j2 < 4; ++j2)
          acc[i][j2] = __builtin_amdgcn_mfma_f32_16x16x32_bf16(
              bfr[j2], afr[i], acc[i][j2], 0, 0, 0);
      __syncthreads();
      cur = nb2;
    }
    // epilogue: sC[mloc][dloc], XOR-swz, coalesced stores.
    {
      unsigned short* Dst = (which == 0) ? Qs : Ks;
      const float sc = (which == 0) ? SCALE_Q : 1.0f;
      unsigned short (*sC)[128] = (unsigned short (*)[128])smem;
      const int b = tm >> 5;
      const long bh = b * 8 + h;
#pragma unroll
      for (int i = 0; i < 4; ++i) {
        const int mloc = wm + i * 16 + m15;
        const int sw8 = (mloc & 7) << 3;
#pragma unroll
        for (int j2 = 0; j2 < 4; ++j2) {
          const int col = (wn + j2 * 16 + (q4 << 2)) ^ sw8;
          uint2 u;
          u.x = pkbf2(acc[i][j2][0] * sc, acc[i][j2][1] * sc);
          u.y = pkbf2(acc[i][j2][2] * sc, acc[i][j2][3] * sc);
          *(uint2*)&sC[mloc][col] = u;
        }
      }
      __syncthreads();
      const int srow = tid >> 4, sch = tid & 15;
      const int rb = (tm & 31) << 7;
#pragma unroll
      for (int ps = 0; ps < 8; ++ps) {
        const int row = ps * 16 + srow;
        const short8 v = *(const short8*)&sC[row][(sch ^ (row & 7)) << 3];
        *(short8*)&Dst[(bh * 4096 + rb + row) * 128 + (sch << 3)] = v;
      }
    }
  }
#undef QKV_STAGE
}

// ---------------- flash attention (unchanged) ------------------------------
__global__ __launch_bounds__(256, 2) void k_flash(
    const unsigned short* __restrict__ Qs, const unsigned short* __restrict__ Ks,
    const unsigned short* __restrict__ Vt,
    const unsigned long long* __restrict__ mbits,
    unsigned short* __restrict__ Ob) {
  __shared__ __align__(16) unsigned short lK[2][16][64][8];   // 2 x 16 KB
  __shared__ __align__(16) unsigned short lV[2][8][128][8];   // 2 x 16 KB

  const int tid = threadIdx.x;
  const int w = tid >> 6, ln = tid & 63;
  const int l31 = ln & 31, hi = ln >> 5, hi4 = hi << 2;
  const bool hib = hi != 0;
  (void)hib;
  const int id = blockIdx.x;
  const int xcd = id & 7, jj = id >> 3;           // 64 blocks per XCD
  const int bh = (xcd << 1) | (jj >> 5);          // 2 bh per XCD (4MB K/V in L2)
  const int rowblk = jj & 31;
  const int rbase = rowblk * 128 + w * 32;
  const int qrow = rbase + l31;

  const unsigned short* Qbh = Qs + (long)bh * 524288;
  const unsigned short* Kbh = Ks + (long)bh * 524288;
  const unsigned short* Vbh = Vt + (long)bh * 524288;

  short8 qf[8];
#pragma unroll
  for (int ks = 0; ks < 8; ++ks)
    qf[ks] = *(const short8*)(Qbh + (long)qrow * 128 + ks * 16 + hi * 8);

  f32x16 o[4];
#pragma unroll
  for (int d = 0; d < 4; ++d)
#pragma unroll
    for (int r = 0; r < 16; ++r) o[d][r] = 0.f;
  float lacc = 0.f;

  const bool maskblk = rowblk < 16;   // rows 0..2047

#define STAGE_KV(dst, kvoff)                                              \
  {                                                                       \
    _Pragma("unroll")                                                     \
    for (int c = 0; c < 4; ++c) {                                         \
      const int p = ((c * 4 + w) << 10) + (ln << 4);                      \
      const int cs = p >> 10;                                             \
      const int j = (p & 1023) >> 4;                                      \
      gload_lds16(Kbh + (long)((kvoff) + j) * 128 + cs * 8,               \
                  (char*)&lK[dst][0][0][0] + p);                          \
    }                                                                     \
    _Pragma("unroll")                                                     \
    for (int c = 0; c < 4; ++c) {                                         \
      const int p = ((c * 4 + w) << 10) + (ln << 4);                      \
      const int cv = p >> 11;                                             \
      const int dv = (p & 2047) >> 4;                                     \
      gload_lds16(Vbh + (long)dv * 4096 + (kvoff) + cv * 8,               \
                  (char*)&lV[dst][0][0][0] + p);                          \
    }                                                                     \
  }

#if __has_builtin(__builtin_amdgcn_permlane32_swap)
#define PLSWAP(a, b)                                                      \
  {                                                                       \
    uint2v r_ = __builtin_amdgcn_permlane32_swap((a), (b), false, false); \
    (a) = r_[0]; (b) = r_[1];                                             \
  }
#else
#define PLSWAP(a, b)                                                      \
  {                                                                       \
    const unsigned pa_ = (unsigned)__shfl_xor((int)(a), 32);              \
    const unsigned pb_ = (unsigned)__shfl_xor((int)(b), 32);              \
    const unsigned na_ = hib ? pb_ : (a);                                 \
    const unsigned nb_ = hib ? (b) : pa_;                                 \
    (a) = na_; (b) = nb_;                                                 \
  }
#endif

  STAGE_KV(0, 0);
  __syncthreads();

  int cur = 0;
  for (int kv = 0; kv < 4096; kv += 64) {
    unsigned long long mw = 0ull;
    const bool domask = maskblk && (kv < 2048);
    if (domask) mw = mbits[(long)qrow * 32 + (kv >> 6)];

    const int nb = cur ^ 1;
    if (kv + 64 < 4096) STAGE_KV(nb, kv + 64);

    f32x16 s0, s1;
#pragma unroll
    for (int r = 0; r < 16; ++r) { s0[r] = 0.f; s1[r] = 0.f; }
    __builtin_amdgcn_s_setprio(1);
#pragma unroll
    for (int ks = 0; ks < 8; ++ks) {
      const short8 kf0 = *(const short8*)&lK[cur][ks * 2 + hi][l31][0];
      const short8 kf1 = *(const short8*)&lK[cur][ks * 2 + hi][32 + l31][0];
      s0 = __builtin_amdgcn_mfma_f32_32x32x16_bf16(kf0, qf[ks], s0, 0, 0, 0);
      s1 = __builtin_amdgcn_mfma_f32_32x32x16_bf16(kf1, qf[ks], s1, 0, 0, 0);
    }
    __builtin_amdgcn_s_setprio(0);

    const unsigned mlo = ((unsigned)mw) >> hi4;
    const unsigned mhi = ((unsigned)(mw >> 32)) >> hi4;

    if (domask) {
#pragma unroll
      for (int r = 0; r < 16; ++r) {
        const int c = ((r >> 2) << 3) + (r & 3);
        if (!((mlo >> c) & 1u)) s0[r] = -1e30f;
      }
    }
    float p0[16];
#pragma unroll
    for (int r = 0; r < 16; ++r) {
      p0[r] = __builtin_amdgcn_exp2f(s0[r]);
      lacc += p0[r];
    }
    unsigned w00 = pkbf2(p0[0], p0[1]),   w01 = pkbf2(p0[2], p0[3]);
    unsigned w10 = pkbf2(p0[4], p0[5]),   w11 = pkbf2(p0[6], p0[7]);
    PLSWAP(w00, w10); PLSWAP(w01, w11);
    unsigned w20 = pkbf2(p0[8], p0[9]),   w21 = pkbf2(p0[10], p0[11]);
    unsigned w30 = pkbf2(p0[12], p0[13]), w31 = pkbf2(p0[14], p0[15]);
    PLSWAP(w20, w30); PLSWAP(w21, w31);
    union { unsigned u[4]; short8 s; } pa0, pa1;
    pa0.u[0] = w00; pa0.u[1] = w01; pa0.u[2] = w10; pa0.u[3] = w11;
    pa1.u[0] = w20; pa1.u[1] = w21; pa1.u[2] = w30; pa1.u[3] = w31;

    __builtin_amdgcn_s_setprio(1);
#pragma unroll
    for (int db = 0; db < 4; ++db) {
      const short8 vf0 = *(const short8*)&lV[cur][hi][db * 32 + l31][0];
      o[db] = __builtin_amdgcn_mfma_f32_32x32x16_bf16(pa0.s, vf0, o[db], 0, 0, 0);
      const short8 vf1 = *(const short8*)&lV[cur][2 + hi][db * 32 + l31][0];
      o[db] = __builtin_amdgcn_mfma_f32_32x32x16_bf16(pa1.s, vf1, o[db], 0, 0, 0);
    }
    __builtin_amdgcn_s_setprio(0);

    if (domask) {
#pragma unroll
      for (int r = 0; r < 16; ++r) {
        const int c = ((r >> 2) << 3) + (r & 3);
        if (!((mhi >> c) & 1u)) s1[r] = -1e30f;
      }
    }
    float p1[16];
#pragma unroll
    for (int r = 0; r < 16; ++r) {
      p1[r] = __builtin_amdgcn_exp2f(s1[r]);
      lacc += p1[r];
    }
    unsigned x00 = pkbf2(p1[0], p1[1]),   x01 = pkbf2(p1[2], p1[3]);
    unsigned x10 = pkbf2(p1[4], p1[5]),   x11 = pkbf2(p1[6], p1[7]);
    PLSWAP(x00, x10); PLSWAP(x01, x11);
    unsigned x20 = pkbf2(p1[8], p1[9]),   x21 = pkbf2(p1[10], p1[11]);
    unsigned x30 = pkbf2(p1[12], p1[13]), x31 = pkbf2(p1[14], p1[15]);
    PLSWAP(x20, x30); PLSWAP(x21, x31);
    union { unsigned u[4]; short8 s; } pa2, pa3;
    pa2.u[0] = x00; pa2.u[1] = x01; pa2.u[2] = x10; pa2.u[3] = x11;
    pa3.u[0] = x20; pa3.u[1] = x21; pa3.u[2] = x30; pa3.u[3] = x31;

    __builtin_amdgcn_s_setprio(1);
#pragma unroll
    for (int db = 0; db < 4; ++db) {
      const short8 vf2 = *(const short8*)&lV[cur][4 + hi][db * 32 + l31][0];
      o[db] = __builtin_amdgcn_mfma_f32_32x32x16_bf16(pa2.s, vf2, o[db], 0, 0, 0);
      const short8 vf3 = *(const short8*)&lV[cur][6 + hi][db * 32 + l31][0];
      o[db] = __builtin_amdgcn_mfma_f32_32x32x16_bf16(pa3.s, vf3, o[db], 0, 0, 0);
    }
    __builtin_amdgcn_s_setprio(0);

    __syncthreads();
    cur = nb;
  }
#undef STAGE_KV
#undef PLSWAP

  const float lh = lacc + __shfl_xor(lacc, 32);
  const float linv = 1.0f / lh;

  const int b = bh >> 3, h = bh & 7;
#pragma unroll
  for (int r = 0; r < 16; ++r) {
    const int qr = (r & 3) + ((r >> 2) << 3) + hi4;
    const float li = __shfl(linv, qr);
    const int row = rbase + qr;
    unsigned short* op = Ob + ((long)(b * 4096 + row)) * 1024 + h * 128 + l31;
#pragma unroll
    for (int db = 0; db < 4; ++db)
      op[db * 32] = f2bf(o[db][r] * li);
  }
}

// ---------------- out projection (BK=32, dbuf, tm-fastest walk) ------------
__global__ __launch_bounds__(256, 3) void k_proj_gemm(
    const unsigned short* __restrict__ A,   // [8192][1024]
    const unsigned short* __restrict__ Bt,  // [1024][1024]
    const float* __restrict__ bias, float* __restrict__ Out) {
  __shared__ __align__(16) char smem[32768];
  typedef unsigned short stageT[4][128][8];
  stageT* lA = (stageT*)smem;
  stageT* lB = (stageT*)(smem + 16384);
  const int tid = threadIdx.x;
  const int w = tid >> 6, ln = tid & 63;
  const int m15 = ln & 15, q4 = ln >> 4;
  const int wm = (w >> 1) << 6, wn = (w & 1) << 6;
  const int id = blockIdx.x;
  const int xcd = id & 7, j = id >> 3;        // j in [0,64)
  const int tn = j >> 3;                      // 0..7 (slow)
  const int tm = (xcd << 3) + (j & 7);        // 8 tm per XCD (fast)

  f32x4 acc[4][4];
#pragma unroll
  for (int i = 0; i < 4; ++i)
#pragma unroll
    for (int j2 = 0; j2 < 4; ++j2) acc[i][j2] = zero4();

#define PROJ_STAGE(buf, kb)                                               \
  {                                                                       \
    _Pragma("unroll")                                                     \
    for (int c = 0; c < 2; ++c) {                                         \
      const int p = ((c * 4 + w) << 10) + (ln << 4);                      \
      const int g = p >> 11;                                              \
      const int r = (p & 2047) >> 4;                                      \
      gload_lds16(A + ((long)tm * 128 + r) * 1024 + (kb) + g * 8,         \
                  smem + (buf) * 8192 + p);                               \
      gload_lds16(Bt + ((long)tn * 128 + r) * 1024 + (kb) + g * 8,        \
                  smem + 16384 + (buf) * 8192 + p);                       \
    }                                                                     \
  }

  PROJ_STAGE(0, 0);
  __syncthreads();

  int cur = 0;
  for (int kb = 0; kb < 1024; kb += 32) {
    const int nb2 = cur ^ 1;
    if (kb + 32 < 1024) PROJ_STAGE(nb2, kb + 32);
    short8 afr[4], bfr[4];
#pragma unroll
    for (int i = 0; i < 4; ++i)
      afr[i] = *(const short8*)&lA[cur][q4][wm + i * 16 + m15][0];
#pragma unroll
    for (int j2 = 0; j2 < 4; ++j2)
      bfr[j2] = *(const short8*)&lB[cur][q4][wn + j2 * 16 + m15][0];
#pragma unroll
    for (int i = 0; i < 4; ++i)
#pragma unroll
      for (int j2 = 0; j2 < 4; ++j2)
        acc[i][j2] = __builtin_amdgcn_mfma_f32_16x16x32_bf16(
            afr[i], bfr[j2], acc[i][j2], 0, 0, 0);
    __syncthreads();
    cur = nb2;
  }
#undef PROJ_STAGE

  // two-pass epilogue in the 32KB pool: pass p stages rows p*64..p*64+63
  // (f32 [64][128], XOR-swz), reads back row-contiguous + bias.
  {
    float (*sF)[128] = (float (*)[128])smem;
    const int prow = tid >> 5, pch = tid & 31;
    const float4 bv = ((const float4*)bias)[(tn << 5) + pch];
#pragma unroll
    for (int pass = 0; pass < 2; ++pass) {
      __syncthreads();
      if ((w >> 1) == pass) {   // waves whose wm == pass*64
#pragma unroll
        for (int i = 0; i < 4; ++i)
#pragma unroll
          for (int r = 0; r < 4; ++r) {
            const int ml = i * 16 + (q4 << 2) + r;      // 0..63
            const int sw = (ml & 7) << 2;
#pragma unroll
            for (int j2 = 0; j2 < 4; ++j2)
              sF[ml][(wn + j2 * 16 + m15) ^ sw] = acc[i][j2][r];
          }
      }
      __syncthreads();
#pragma unroll
      for (int ps = 0; ps < 8; ++ps) {
        const int rl = (ps << 3) + prow;                // 0..63
        float4 v = *(const float4*)&sF[rl][(pch ^ (rl & 7)) << 2];
        v.x += bv.x; v.y += bv.y; v.z += bv.z; v.w += bv.w;
        const int row = (tm << 7) + (pass << 6) + rl;
        *(float4*)&Out[(long)row * 1024 + (tn << 7) + (pch << 2)] = v;
      }
    }
  }
}

extern "C" void kernel_launch(void* const* d_in, const int* in_sizes, int n_in,
                              void* d_out, int out_size, void* d_ws,
                              size_t ws_size, hipStream_t stream) {
  const float* x = (const float*)d_in[0];
  const float* Wqkv = (const float*)d_in[1];
  const float* Wout = (const float*)d_in[2];
  const float* bout = (const float*)d_in[3];
  const int* mask = (const int*)d_in[4];
  float* out = (float*)d_out;

  char* ws = (char*)d_ws;
  unsigned short* xb     = (unsigned short*)(ws);            // later Ob
  unsigned short* wqkv_t = (unsigned short*)(ws + 16777216);
  unsigned short* wout_t = (unsigned short*)(ws + 23068672);
  unsigned short* Qs     = (unsigned short*)(ws + 25165824);
  unsigned short* Ks     = (unsigned short*)(ws + 41943040);
  unsigned short* Vt     = (unsigned short*)(ws + 58720256);
  unsigned short* Ob     = xb;                         // xb dead after qkv
  unsigned long long* mbits = (unsigned long long*)wqkv_t;  // wqkv_t dead after qkv

  hipLaunchKernelGGL(k_prep, dim3(12288), dim3(256), 0, stream,
                     x, xb, Wqkv, wqkv_t, Wout, wout_t);
  hipLaunchKernelGGL(k_qkv_gemm, dim3(1536), dim3(256), 0, stream,
                     xb, wqkv_t, Qs, Ks, Vt);
  hipLaunchKernelGGL(k_mask_bits, dim3(16384), dim3(256), 0, stream,
                     mask, mbits);
  hipLaunchKernelGGL(k_flash, dim3(512), dim3(256), 0, stream,
                     Qs, Ks, Vt, mbits, Ob);
  hipLaunchKernelGGL(k_proj_gemm, dim3(512), dim3(256), 0, stream,
                     Ob, wout_t, bout, out);
}